// Round 8
// baseline (572.910 us; speedup 1.0000x reference)
//
#include <hip/hip_runtime.h>
#include <hip/hip_bf16.h>

static constexpr int TOTAL = 349525;
static constexpr int OFFS[11] = {0,1,5,21,85,341,1365,5461,21845,87381,349525};
// emb blocks of 64 nodes per level: counts {1,1,1,1,4,16,64,256,1024,4096}
static constexpr int EB64[11] = {0,1,2,3,4,8,24,88,344,1368,5464};
static constexpr size_t HPRE_BYTES = (size_t)(87381 - 85) * 64 * 4;  // levels 4..8 mirror

__device__ __forceinline__ unsigned deint(unsigned v){
  v &= 0x55555555u;
  v = (v | (v>>1)) & 0x33333333u;
  v = (v | (v>>2)) & 0x0F0F0F0Fu;
  v = (v | (v>>4)) & 0x00FF00FFu;
  v = (v | (v>>8)) & 0x0000FFFFu;
  return v;
}
__device__ __forceinline__ unsigned ileave(unsigned v){
  v &= 0xFFFFu;
  v = (v | (v<<8)) & 0x00FF00FFu;
  v = (v | (v<<4)) & 0x0F0F0F0Fu;
  v = (v | (v<<2)) & 0x33333333u;
  v = (v | (v<<1)) & 0x55555555u;
  return v;
}
// XOR-swizzled LDS tile addressing: pitch 64 floats, 16B granule XOR (T2-style)
__device__ __forceinline__ int swz(int row, int f4){
  return row*64 + ((f4 ^ (row & 7)) << 2);
}

// ---------- in_proj: h[g] = concat(f, posenc) @ W(40x64) + b ----------
// lane = node, wave = 16-ch slice; W via wave-uniform scalar loads.
__global__ __launch_bounds__(256) void k_inproj(const float* __restrict__ feat,
    const float* __restrict__ W, const float* __restrict__ B,
    float* __restrict__ h, float* __restrict__ hpre){
  __shared__ float Alt[64*64];
  int t = threadIdx.x;
  int base = blockIdx.x * 64;
  if (t < 64){
    int g = base + t;
    int rb = t*64, sw = (t & 7) << 2;
    if (g < TOTAL){
      int d = 0;
      #pragma unroll
      for (int i=1;i<=9;++i) if (g >= OFFS[i]) d = i;
      int local = g - OFFS[d];
      unsigned ix = deint((unsigned)local), iy = deint(((unsigned)local)>>1);
      float inv = 1.f/(float)(1<<d);
      float px = ((float)ix+0.5f)*inv, py = ((float)iy+0.5f)*inv;
      float pd = (float)d*(1.f/9.f);
      Alt[rb + ((0^sw))    ] = feat[g];
      Alt[rb + ((0^sw)) + 1] = px;
      Alt[rb + ((0^sw)) + 2] = py;
      Alt[rb + ((0^sw)) + 3] = pd;
      float p3[3] = {px,py,pd};
      #pragma unroll
      for (int c=0;c<3;++c){
        float s,co; __sincosf(6.28318530717958647692f*p3[c], &s, &co);
        #pragma unroll
        for (int f=0;f<6;++f){
          int ks = 4 + c*12 + f, kc = ks + 6;
          Alt[rb + (((ks>>2)<<2)^sw) + (ks&3)] = s;
          Alt[rb + (((kc>>2)<<2)^sw) + (kc&3)] = co;
          float s2=2.f*s*co, c2=1.f-2.f*s*s; s=s2; co=c2;
        }
      }
    } else {
      #pragma unroll
      for (int k=0;k<40;++k) Alt[rb + (((k>>2)<<2)^sw) + (k&3)] = 0.f;
    }
  }
  __syncthreads();
  int wave = __builtin_amdgcn_readfirstlane((int)(threadIdx.x >> 6));
  int lane = t & 63;
  const float* Wv = W + wave*16;
  float acc[16];
  {
    const float* bp = B + wave*16;
    #pragma unroll
    for (int c=0;c<16;++c) acc[c] = bp[c];
  }
  #pragma unroll 2
  for (int k4=0;k4<10;++k4){
    float4 a = *(const float4*)&Alt[swz(lane,k4)];
    float av[4] = {a.x,a.y,a.z,a.w};
    #pragma unroll
    for (int j=0;j<4;++j){
      const float* wr = Wv + (k4*4+j)*64;
      float wv[16];
      float4 w0 = *(const float4*)(wr);
      float4 w1 = *(const float4*)(wr+4);
      float4 w2 = *(const float4*)(wr+8);
      float4 w3 = *(const float4*)(wr+12);
      wv[0]=w0.x; wv[1]=w0.y; wv[2]=w0.z; wv[3]=w0.w;
      wv[4]=w1.x; wv[5]=w1.y; wv[6]=w1.z; wv[7]=w1.w;
      wv[8]=w2.x; wv[9]=w2.y; wv[10]=w2.z; wv[11]=w2.w;
      wv[12]=w3.x; wv[13]=w3.y; wv[14]=w3.z; wv[15]=w3.w;
      float aj = av[j];
      #pragma unroll
      for (int c=0;c<16;++c) acc[c] += aj*wv[c];
    }
  }
  int g = base + lane;
  if (g < TOTAL){
    float4 o0 = make_float4(acc[0],acc[1],acc[2],acc[3]);
    float4 o1 = make_float4(acc[4],acc[5],acc[6],acc[7]);
    float4 o2 = make_float4(acc[8],acc[9],acc[10],acc[11]);
    float4 o3 = make_float4(acc[12],acc[13],acc[14],acc[15]);
    float* dst = h + (size_t)g*64 + wave*16;
    *(float4*)dst = o0; *(float4*)(dst+4) = o1;
    *(float4*)(dst+8) = o2; *(float4*)(dst+12) = o3;
    if (hpre && g >= OFFS[4] && g < OFFS[9]){   // immutable parent mirror (race fix)
      float* dp = hpre + (size_t)(g - OFFS[4])*64 + wave*16;
      *(float4*)dp = o0; *(float4*)(dp+4) = o1;
      *(float4*)(dp+8) = o2; *(float4*)(dp+12) = o3;
    }
  }
}

// ---------- conv (halo, fused pool, scalar-W): h[L] = relu(gather9(pool)@W + b) ----------
__global__ __launch_bounds__(256) void k_conv(float* __restrict__ h,
    const float* __restrict__ hPar,   // parent rows for level L (pre-conv mirror or h)
    const float* __restrict__ W, const float* __restrict__ Bb,
    int N, int offL, int offC, int lbits){
  __shared__ float halo[100*64];
  __shared__ int hkey[100];
  int t = threadIdx.x;
  int nb = blockIdx.x * 64;
  int res = 1 << lbits;
  if (t < 100){
    int i = t % 10, j = t / 10;
    int gx = (int)deint((unsigned)nb) - 1 + i;
    int gy = (int)deint(((unsigned)nb)>>1) - 1 + j;
    bool ok = (gx>=0 && gy>=0 && gx<res && gy<res);
    hkey[t] = ok ? (int)(ileave((unsigned)gx) | (ileave((unsigned)gy)<<1)) : -1;
  }
  __syncthreads();
  const float* hC = h + (size_t)offC*64;
  for (int e = t; e < 1600; e += 256){
    int hi = e >> 4, u = e & 15;
    int key = hkey[hi];
    float4 r = make_float4(0.f,0.f,0.f,0.f);
    if (key >= 0){
      const float4* c = (const float4*)(hC + (size_t)(4*key)*64) + u;
      float4 c0 = c[0], c1 = c[16], c2 = c[32], c3 = c[48];
      float4 pr = *((const float4*)(hPar + (size_t)key*64) + u);
      r.x = 0.25f*(c0.x+c1.x+c2.x+c3.x) + pr.x;
      r.y = 0.25f*(c0.y+c1.y+c2.y+c3.y) + pr.y;
      r.z = 0.25f*(c0.z+c1.z+c2.z+c3.z) + pr.z;
      r.w = 0.25f*(c0.w+c1.w+c2.w+c3.w) + pr.w;
    }
    *(float4*)&halo[swz(hi,u)] = r;
  }
  __syncthreads();
  int wave = __builtin_amdgcn_readfirstlane((int)(threadIdx.x>>6));
  int lane = t & 63;
  const float* Wv = W + wave*16;
  int lx = (int)deint((unsigned)lane), ly = (int)deint(((unsigned)lane)>>1);
  int r0 = ly*10 + lx;
  float acc[16];
  #pragma unroll
  for (int c=0;c<16;++c) acc[c] = 0.f;
  int m = 0;
  #pragma unroll 1
  for (int dy=0;dy<3;++dy){
    #pragma unroll 1
    for (int dx=0;dx<3;++dx){
      int rr = r0 + dy*10 + dx;
      const float* Wm = Wv + m*4096;
      #pragma unroll 2
      for (int k4=0;k4<16;++k4){
        float4 a = *(const float4*)&halo[swz(rr,k4)];
        float av[4] = {a.x,a.y,a.z,a.w};
        #pragma unroll
        for (int j=0;j<4;++j){
          const float* wr = Wm + (k4*4+j)*64;
          float wv[16];
          float4 w0 = *(const float4*)(wr);
          float4 w1 = *(const float4*)(wr+4);
          float4 w2 = *(const float4*)(wr+8);
          float4 w3 = *(const float4*)(wr+12);
          wv[0]=w0.x; wv[1]=w0.y; wv[2]=w0.z; wv[3]=w0.w;
          wv[4]=w1.x; wv[5]=w1.y; wv[6]=w1.z; wv[7]=w1.w;
          wv[8]=w2.x; wv[9]=w2.y; wv[10]=w2.z; wv[11]=w2.w;
          wv[12]=w3.x; wv[13]=w3.y; wv[14]=w3.z; wv[15]=w3.w;
          float aj = av[j];
          #pragma unroll
          for (int c=0;c<16;++c) acc[c] += aj*wv[c];
        }
      }
      ++m;
    }
  }
  int node = nb + lane;
  if (node < N){
    const float* bp = Bb + wave*16;
    float* dst = h + (size_t)(offL + node)*64 + wave*16;
    float ov[16];
    #pragma unroll
    for (int c=0;c<16;++c){
      float v = acc[c] + bp[c];
      ov[c] = v > 0.f ? v : 0.f;
    }
    *(float4*)dst      = make_float4(ov[0],ov[1],ov[2],ov[3]);
    *(float4*)(dst+4)  = make_float4(ov[4],ov[5],ov[6],ov[7]);
    *(float4*)(dst+8)  = make_float4(ov[8],ov[9],ov[10],ov[11]);
    *(float4*)(dst+12) = make_float4(ov[12],ov[13],ov[14],ov[15]);
  }
}

// ---------- fused tail: d=4..1, one block (unchanged from round 7) ----------
__global__ __launch_bounds__(256) void k_tail(float* __restrict__ h,
    const float* __restrict__ convW, const float* __restrict__ convB){
  __shared__ float Pt[65][68];    // row 64 = zero row for invalid neighbors
  __shared__ float Wl[64][68];
  int t = threadIdx.x;
  #pragma unroll
  for (int d = 4; d >= 1; --d){
    const int L = d - 1;
    const int Np = 1 << (2*L);   // 64,16,4,1
    for (int e = t; e < Np*16; e += 256){
      int node = e >> 4, u = e & 15;
      const float4* c = (const float4*)(h + (size_t)(OFFS[d] + 4*node)*64) + u;
      float4 c0 = c[0], c1 = c[16], c2 = c[32], c3 = c[48];
      float4 pr = *((const float4*)(h + (size_t)(OFFS[L] + node)*64) + u);
      float4 r;
      r.x = 0.25f*(c0.x+c1.x+c2.x+c3.x) + pr.x;
      r.y = 0.25f*(c0.y+c1.y+c2.y+c3.y) + pr.y;
      r.z = 0.25f*(c0.z+c1.z+c2.z+c3.z) + pr.z;
      r.w = 0.25f*(c0.w+c1.w+c2.w+c3.w) + pr.w;
      *(float4*)&Pt[node][u*4] = r;
    }
    if (t < 17) *(float4*)&Pt[64][t*4] = make_float4(0.f,0.f,0.f,0.f);
    __syncthreads();
    if (L == 0){
      if (t < 16) ((float4*)h)[t] = *(const float4*)&Pt[0][t*4];
      break;
    }
    const int R = (L == 3) ? 2 : 1;
    const int res = 1 << L;
    int tr = t >> 3, tc = t & 7;
    bool act = (tr*R) < Np;
    float acc[2][8];
    #pragma unroll
    for (int i=0;i<2;++i)
      #pragma unroll
      for (int c=0;c<8;++c) acc[i][c] = 0.f;
    unsigned ixs[2] = {0,0}, iys[2] = {0,0};
    if (act){
      #pragma unroll
      for (int i=0;i<R;++i){
        unsigned node = (unsigned)(tr*R + i);
        ixs[i] = deint(node); iys[i] = deint(node >> 1);
      }
    }
    const float* WL = convW + (size_t)L*36864;
    float4 rW0, rW1, rW2, rW3;
    {
      const float4* W4 = (const float4*)WL;
      rW0 = W4[t*4]; rW1 = W4[t*4+1]; rW2 = W4[t*4+2]; rW3 = W4[t*4+3];
    }
    for (int m=0;m<9;++m){
      __syncthreads();
      {
        int kk = t >> 2, c0 = (t & 3)*16;
        *(float4*)&Wl[kk][c0]      = rW0;
        *(float4*)&Wl[kk][c0 + 4]  = rW1;
        *(float4*)&Wl[kk][c0 + 8]  = rW2;
        *(float4*)&Wl[kk][c0 + 12] = rW3;
      }
      if (m < 8){
        const float4* W4 = (const float4*)(WL + (size_t)(m+1)*4096);
        rW0 = W4[t*4]; rW1 = W4[t*4+1]; rW2 = W4[t*4+2]; rW3 = W4[t*4+3];
      }
      __syncthreads();
      if (act){
        int dy = m/3 - 1, dx = m%3 - 1;
        int key[2];
        #pragma unroll
        for (int i=0;i<R;++i){
          int nx = (int)ixs[i] + dx, ny = (int)iys[i] + dy;
          key[i] = (nx>=0 && ny>=0 && nx<res && ny<res)
                 ? (int)(ileave((unsigned)nx) | (ileave((unsigned)ny) << 1)) : 64;
        }
        #pragma unroll 2
        for (int k4=0;k4<16;++k4){
          float av4[2][4];
          #pragma unroll
          for (int i=0;i<R;++i){
            float4 aa = *(const float4*)&Pt[key[i]][k4*4];
            av4[i][0]=aa.x; av4[i][1]=aa.y; av4[i][2]=aa.z; av4[i][3]=aa.w;
          }
          #pragma unroll
          for (int j=0;j<4;++j){
            float4 lo = *(const float4*)&Wl[k4*4+j][tc*8];
            float4 hi = *(const float4*)&Wl[k4*4+j][tc*8+4];
            float wv[8];
            wv[0]=lo.x; wv[1]=lo.y; wv[2]=lo.z; wv[3]=lo.w;
            wv[4]=hi.x; wv[5]=hi.y; wv[6]=hi.z; wv[7]=hi.w;
            #pragma unroll
            for (int i=0;i<R;++i){
              float a = av4[i][j];
              #pragma unroll
              for (int c=0;c<8;++c) acc[i][c] += a*wv[c];
            }
          }
        }
      }
    }
    __syncthreads();
    if (act){
      #pragma unroll
      for (int i=0;i<R;++i){
        int node = tr*R + i;
        float ov[8];
        #pragma unroll
        for (int c=0;c<8;++c){
          float v = acc[i][c] + convB[L*64 + tc*8 + c];
          ov[c] = v > 0.f ? v : 0.f;
        }
        float* dst = &h[(size_t)(OFFS[L] + node)*64 + tc*8];
        *(float4*)dst       = *(const float4*)&ov[0];
        *(float4*)(dst + 4) = *(const float4*)&ov[4];
      }
    }
    __syncthreads();
  }
}

// ---------- emb + layernorm + gain (scalar-W, lane=node, wave=16ch) ----------
__global__ __launch_bounds__(256) void k_emb(float* __restrict__ h,
    const float* __restrict__ embW, const float* __restrict__ embB,
    const float* __restrict__ lng, const float* __restrict__ lnb,
    const float* __restrict__ gain){
  __shared__ float Alt[64*64];
  __shared__ float sq[64*9];
  int bb = blockIdx.x;
  int d = 0;
  #pragma unroll
  for (int i=1;i<=9;++i) if (bb >= EB64[i]) d = i;
  int nb = (bb - EB64[d]) * 64;
  int N = 1 << (2*d);
  int off = OFFS[d];
  int t = threadIdx.x;
  #pragma unroll
  for (int e0=0;e0<4;++e0){
    int e = t + e0*256;
    int node = e >> 4, u = e & 15;
    int g = nb + node;
    float4 v = (g < N) ? *((const float4*)(h + (size_t)(off+g)*64) + u)
                       : make_float4(0.f,0.f,0.f,0.f);
    *(float4*)&Alt[swz(node,u)] = v;
  }
  __syncthreads();
  int wave = __builtin_amdgcn_readfirstlane((int)(threadIdx.x>>6));
  int lane = t & 63;
  const float* Wv = embW + (size_t)d*4096 + wave*16;
  float acc[16];
  {
    const float* bp = embB + d*64 + wave*16;
    #pragma unroll
    for (int c=0;c<16;++c) acc[c] = bp[c];
  }
  #pragma unroll 2
  for (int k4=0;k4<16;++k4){
    float4 a = *(const float4*)&Alt[swz(lane,k4)];
    float av[4] = {a.x,a.y,a.z,a.w};
    #pragma unroll
    for (int j=0;j<4;++j){
      const float* wr = Wv + (k4*4+j)*64;
      float wv[16];
      float4 w0 = *(const float4*)(wr);
      float4 w1 = *(const float4*)(wr+4);
      float4 w2 = *(const float4*)(wr+8);
      float4 w3 = *(const float4*)(wr+12);
      wv[0]=w0.x; wv[1]=w0.y; wv[2]=w0.z; wv[3]=w0.w;
      wv[4]=w1.x; wv[5]=w1.y; wv[6]=w1.z; wv[7]=w1.w;
      wv[8]=w2.x; wv[9]=w2.y; wv[10]=w2.z; wv[11]=w2.w;
      wv[12]=w3.x; wv[13]=w3.y; wv[14]=w3.z; wv[15]=w3.w;
      float aj = av[j];
      #pragma unroll
      for (int c=0;c<16;++c) acc[c] += aj*wv[c];
    }
  }
  float s = 0.f, q = 0.f;
  #pragma unroll
  for (int c=0;c<16;++c){ s += acc[c]; q += acc[c]*acc[c]; }
  sq[lane*9 + wave*2]     = s;
  sq[lane*9 + wave*2 + 1] = q;
  __syncthreads();
  float S = sq[lane*9+0] + sq[lane*9+2] + sq[lane*9+4] + sq[lane*9+6];
  float Q = sq[lane*9+1] + sq[lane*9+3] + sq[lane*9+5] + sq[lane*9+7];
  float mu = S * 0.015625f;
  float var = Q * 0.015625f - mu*mu;
  float rs = rsqrtf(var + 1e-5f);
  int g = nb + lane;
  if (g < N){
    const float* gp = lng + d*64 + wave*16;
    const float* lp = lnb + d*64 + wave*16;
    float gn = gain[d];
    float ov[16];
    #pragma unroll
    for (int c=0;c<16;++c)
      ov[c] = ((acc[c] - mu) * rs * gp[c] + lp[c]) * gn;
    float* dst = h + (size_t)(off + g)*64 + wave*16;
    *(float4*)dst      = make_float4(ov[0],ov[1],ov[2],ov[3]);
    *(float4*)(dst+4)  = make_float4(ov[4],ov[5],ov[6],ov[7]);
    *(float4*)(dst+8)  = make_float4(ov[8],ov[9],ov[10],ov[11]);
    *(float4*)(dst+12) = make_float4(ov[12],ov[13],ov[14],ov[15]);
  }
}

extern "C" void kernel_launch(void* const* d_in, const int* in_sizes, int n_in,
                              void* d_out, int out_size, void* d_ws, size_t ws_size,
                              hipStream_t stream) {
  (void)in_sizes; (void)n_in; (void)out_size;
  const float* feat  = (const float*)d_in[0];
  const float* ipW   = (const float*)d_in[1];
  const float* ipB   = (const float*)d_in[2];
  const float* convW = (const float*)d_in[3];
  const float* convB = (const float*)d_in[4];
  const float* embW  = (const float*)d_in[5];
  const float* embB  = (const float*)d_in[6];
  const float* lng   = (const float*)d_in[7];
  const float* lnb   = (const float*)d_in[8];
  const float* gain  = (const float*)d_in[9];
  float* h = (float*)d_out;            // h lives in d_out (f32), emb runs in place
  bool safe = ws_size >= HPRE_BYTES;   // pre-conv parent mirror fits in workspace?
  float* hpre = safe ? (float*)d_ws : nullptr;

  k_inproj<<<(TOTAL + 63)/64, 256, 0, stream>>>(feat, ipW, ipB, h, hpre);

  // levels L=8..4: halo conv with fused pool; parent rows from immutable mirror
  for (int L = 8; L >= 4; --L){
    int Np = 1 << (2*L);
    const float* hPar = safe ? (hpre + (size_t)(OFFS[L] - OFFS[4])*64)
                             : (h + (size_t)OFFS[L]*64);
    k_conv<<<Np/64, 256, 0, stream>>>(h, hPar, convW + (size_t)L*36864,
        convB + (size_t)L*64, Np, OFFS[L], OFFS[L+1], L);
  }

  // d=4..1 fused single-block tail
  k_tail<<<1, 256, 0, stream>>>(h, convW, convB);

  k_emb<<<5464, 256, 0, stream>>>(h, embW, embB, lng, lnb, gain);
}

// Round 9
// 258.571 us; speedup vs baseline: 2.2157x; 2.2157x over previous
//
#include <hip/hip_runtime.h>
#include <hip/hip_bf16.h>

static constexpr int TOTAL = 349525;
static constexpr int OFFS[11] = {0,1,5,21,85,341,1365,5461,21845,87381,349525};
// emb blocks of 128 nodes per level: counts {1,1,1,1,2,8,32,128,512,2048}
static constexpr int EBLK[11] = {0,1,2,3,4,6,14,46,174,686,2734};
// Wfrag: 5 levels (L=4..8) x 9 m x 2 ks x 4 cb x 64 lanes x 8 bf16
static constexpr size_t WFRAG_HALF = 5*9*2*4*64*8;          // 184320 ushorts
static constexpr size_t WFRAG_BYTES = WFRAG_HALF*2*2;       // 737280 B
static constexpr size_t HPRE_BYTES = (size_t)(87381-85)*64*4;

typedef __attribute__((ext_vector_type(8))) short short8;
typedef __attribute__((ext_vector_type(4))) float f32x4;

__device__ __forceinline__ unsigned deint(unsigned v){
  v &= 0x55555555u;
  v = (v | (v>>1)) & 0x33333333u;
  v = (v | (v>>2)) & 0x0F0F0F0Fu;
  v = (v | (v>>4)) & 0x00FF00FFu;
  v = (v | (v>>8)) & 0x0000FFFFu;
  return v;
}
__device__ __forceinline__ unsigned ileave(unsigned v){
  v &= 0xFFFFu;
  v = (v | (v<<8)) & 0x00FF00FFu;
  v = (v | (v<<4)) & 0x0F0F0F0Fu;
  v = (v | (v<<2)) & 0x33333333u;
  v = (v | (v<<1)) & 0x55555555u;
  return v;
}
// f32 -> bf16 (RNE) and back
__device__ __forceinline__ unsigned short f2bh(float x){
  unsigned u = __float_as_uint(x);
  return (unsigned short)((u + 0x7FFFu + ((u>>16)&1u)) >> 16);
}
__device__ __forceinline__ float bh2f(unsigned short h){
  return __uint_as_float(((unsigned)h) << 16);
}

// ---------- W prep: conv_W[L=4..8] -> fragment-ordered bf16 hi/lo ----------
// frag idx = ((((Lp*9+m)*2+ks)*4+cb)*64+l); value[j] = W[L][m*64 + ks*32+(l>>4)*8+j][cb*16+(l&15)]
__global__ __launch_bounds__(256) void k_wprep(const float* __restrict__ convW,
    unsigned short* __restrict__ WH, unsigned short* __restrict__ WLo){
  int tid = blockIdx.x*256 + threadIdx.x;       // 23040 total
  int l  = tid & 63;
  int cb = (tid>>6) & 3;
  int ks = (tid>>8) & 1;
  int x  = tid >> 9;
  int m  = x % 9, Lp = x / 9;                   // Lp 0..4 -> L=Lp+4
  int k0 = ks*32 + (l>>4)*8;
  int ch = cb*16 + (l&15);
  const float* src = convW + (size_t)(Lp+4)*36864 + (size_t)(m*64 + k0)*64 + ch;
  unsigned short hv[8], lv[8];
  #pragma unroll
  for (int j=0;j<8;++j){
    float v = src[(size_t)j*64];
    unsigned short h = f2bh(v);
    hv[j] = h;
    lv[j] = f2bh(v - bh2f(h));
  }
  short8 vh = {(short)hv[0],(short)hv[1],(short)hv[2],(short)hv[3],
               (short)hv[4],(short)hv[5],(short)hv[6],(short)hv[7]};
  short8 vl = {(short)lv[0],(short)lv[1],(short)lv[2],(short)lv[3],
               (short)lv[4],(short)lv[5],(short)lv[6],(short)lv[7]};
  *(short8*)(WH  + (size_t)tid*8) = vh;
  *(short8*)(WLo + (size_t)tid*8) = vl;
}

// ---------- in_proj (round-7 form + hpre mirror) ----------
__global__ __launch_bounds__(256) void k_inproj(const float* __restrict__ feat,
    const float* __restrict__ W, const float* __restrict__ B,
    float* __restrict__ h, float* __restrict__ hpre){
  __shared__ float Alt[128][44];
  __shared__ float Wl[40][68];
  int t = threadIdx.x;
  int base = blockIdx.x * 128;
  for (int idx = t; idx < 40*64; idx += 256)
    Wl[idx >> 6][idx & 63] = W[idx];
  if (t < 128){
    int g = base + t;
    float* row = Alt[t];
    if (g < TOTAL){
      int d = 0;
      #pragma unroll
      for (int i = 1; i <= 9; ++i) if (g >= OFFS[i]) d = i;
      int local = g - OFFS[d];
      unsigned ix = deint((unsigned)local), iy = deint(((unsigned)local) >> 1);
      float inv = 1.0f / (float)(1 << d);
      float px = ((float)ix + 0.5f) * inv;
      float py = ((float)iy + 0.5f) * inv;
      float pd = (float)d * (1.0f/9.0f);
      row[0] = feat[g]; row[1] = px; row[2] = py; row[3] = pd;
      float p3[3] = {px, py, pd};
      #pragma unroll
      for (int c = 0; c < 3; ++c){
        float s, co;
        __sincosf(6.28318530717958647692f * p3[c], &s, &co);
        float* rb = row + 4 + c*12;
        #pragma unroll
        for (int f = 0; f < 6; ++f){
          rb[f] = s; rb[6+f] = co;
          float s2 = 2.f*s*co, c2 = 1.f - 2.f*s*s;
          s = s2; co = c2;
        }
      }
    } else {
      #pragma unroll
      for (int k = 0; k < 40; ++k) row[k] = 0.f;
    }
  }
  __syncthreads();
  int tr = t >> 3, tc = t & 7;
  float acc[4][8];
  #pragma unroll
  for (int i=0;i<4;++i)
    #pragma unroll
    for (int c=0;c<8;++c) acc[i][c] = 0.f;
  #pragma unroll 2
  for (int k4 = 0; k4 < 10; ++k4){
    float av4[4][4];
    #pragma unroll
    for (int i=0;i<4;++i){
      float4 aa = *(const float4*)&Alt[tr*4+i][k4*4];
      av4[i][0]=aa.x; av4[i][1]=aa.y; av4[i][2]=aa.z; av4[i][3]=aa.w;
    }
    #pragma unroll
    for (int j=0;j<4;++j){
      float4 lo = *(const float4*)&Wl[k4*4+j][tc*8];
      float4 hi = *(const float4*)&Wl[k4*4+j][tc*8+4];
      float wv[8];
      wv[0]=lo.x; wv[1]=lo.y; wv[2]=lo.z; wv[3]=lo.w;
      wv[4]=hi.x; wv[5]=hi.y; wv[6]=hi.z; wv[7]=hi.w;
      #pragma unroll
      for (int i=0;i<4;++i){
        float a = av4[i][j];
        #pragma unroll
        for (int c=0;c<8;++c) acc[i][c] += a*wv[c];
      }
    }
  }
  #pragma unroll
  for (int i=0;i<4;++i){
    int g = base + tr*4 + i;
    if (g >= TOTAL) continue;
    float ov[8];
    #pragma unroll
    for (int c=0;c<8;++c) ov[c] = acc[i][c] + B[tc*8+c];
    float* dst = &h[(size_t)g*64 + tc*8];
    *(float4*)dst       = *(const float4*)&ov[0];
    *(float4*)(dst + 4) = *(const float4*)&ov[4];
    if (hpre && g >= OFFS[4] && g < OFFS[9]){
      float* dp = hpre + (size_t)(g - OFFS[4])*64 + tc*8;
      *(float4*)dp       = *(const float4*)&ov[0];
      *(float4*)(dp + 4) = *(const float4*)&ov[4];
    }
  }
}

// ---------- conv (halo + fused pool + MFMA bf16-split) ----------
// LDS halo bf16 hi/lo, pitch 72 (144B -> rows feed banks). Zero barriers in m-loop.
__global__ __launch_bounds__(256) void k_conv(float* __restrict__ h,
    const float* __restrict__ hPar,
    const unsigned short* __restrict__ WHl, const unsigned short* __restrict__ WLl,
    const float* __restrict__ Bb, int N, int offL, int offC, int lbits){
  __shared__ unsigned short haloH[100*72];
  __shared__ unsigned short haloL[100*72];
  __shared__ int hkey[100];
  int t = threadIdx.x;
  int nb = blockIdx.x * 64;
  int res = 1 << lbits;
  if (t < 100){
    int i = t % 10, j = t / 10;
    int gx = (int)deint((unsigned)nb) - 1 + i;
    int gy = (int)deint(((unsigned)nb)>>1) - 1 + j;
    bool ok = (gx>=0 && gy>=0 && gx<res && gy<res);
    hkey[t] = ok ? (int)(ileave((unsigned)gx) | (ileave((unsigned)gy)<<1)) : -1;
  }
  __syncthreads();
  const float* hC = h + (size_t)offC*64;
  for (int e = t; e < 1600; e += 256){
    int hi_ = e >> 4, u = e & 15;
    int key = hkey[hi_];
    float4 r = make_float4(0.f,0.f,0.f,0.f);
    if (key >= 0){
      const float4* c = (const float4*)(hC + (size_t)(4*key)*64) + u;
      float4 c0 = c[0], c1 = c[16], c2 = c[32], c3 = c[48];
      float4 pr = *((const float4*)(hPar + (size_t)key*64) + u);
      r.x = 0.25f*(c0.x+c1.x+c2.x+c3.x) + pr.x;
      r.y = 0.25f*(c0.y+c1.y+c2.y+c3.y) + pr.y;
      r.z = 0.25f*(c0.z+c1.z+c2.z+c3.z) + pr.z;
      r.w = 0.25f*(c0.w+c1.w+c2.w+c3.w) + pr.w;
    }
    unsigned short h0=f2bh(r.x), h1=f2bh(r.y), h2=f2bh(r.z), h3=f2bh(r.w);
    ushort4 rh = make_ushort4(h0,h1,h2,h3);
    ushort4 rl = make_ushort4(f2bh(r.x - bh2f(h0)), f2bh(r.y - bh2f(h1)),
                              f2bh(r.z - bh2f(h2)), f2bh(r.w - bh2f(h3)));
    *(ushort4*)&haloH[hi_*72 + u*4] = rh;
    *(ushort4*)&haloL[hi_*72 + u*4] = rl;
  }
  __syncthreads();

  int cb   = __builtin_amdgcn_readfirstlane((int)(threadIdx.x >> 6));  // wave = 16-ch block
  int lane = t & 63;
  int q = lane >> 4;
  int chl = cb*16 + (lane & 15);
  // per-lane node coords for the 4 node-blocks (A row = lane&15 within each 16-tile)
  int lx0,ly0,lx1,ly1,lx2,ly2,lx3,ly3;
  {
    int n0 = (lane&15), n1 = 16+(lane&15), n2 = 32+(lane&15), n3 = 48+(lane&15);
    lx0=(int)deint((unsigned)n0); ly0=(int)deint(((unsigned)n0)>>1);
    lx1=(int)deint((unsigned)n1); ly1=(int)deint(((unsigned)n1)>>1);
    lx2=(int)deint((unsigned)n2); ly2=(int)deint(((unsigned)n2)>>1);
    lx3=(int)deint((unsigned)n3); ly3=(int)deint(((unsigned)n3)>>1);
  }
  f32x4 acc0 = {0.f,0.f,0.f,0.f}, acc1 = acc0, acc2 = acc0, acc3 = acc0;

  #pragma unroll 1
  for (int dy=0;dy<3;++dy){
    #pragma unroll 1
    for (int dx=0;dx<3;++dx){
      int m = dy*3 + dx;
      int r0 = (ly0+dy)*10 + lx0+dx;
      int r1 = (ly1+dy)*10 + lx1+dx;
      int r2 = (ly2+dy)*10 + lx2+dx;
      int r3 = (ly3+dy)*10 + lx3+dx;
      #pragma unroll
      for (int ks=0;ks<2;++ks){
        const unsigned short* fp = WHl + ((size_t)((m*2+ks)*4 + cb)*64 + lane)*8;
        const unsigned short* fq = WLl + ((size_t)((m*2+ks)*4 + cb)*64 + lane)*8;
        short8 bh = *(const short8*)fp;
        short8 bl = *(const short8*)fq;
        int so = (ks*4 + q)*8;                  // ushort offset within row
        short8 ah0 = *(const short8*)&haloH[r0*72 + so];
        short8 al0 = *(const short8*)&haloL[r0*72 + so];
        short8 ah1 = *(const short8*)&haloH[r1*72 + so];
        short8 al1 = *(const short8*)&haloL[r1*72 + so];
        short8 ah2 = *(const short8*)&haloH[r2*72 + so];
        short8 al2 = *(const short8*)&haloL[r2*72 + so];
        short8 ah3 = *(const short8*)&haloH[r3*72 + so];
        short8 al3 = *(const short8*)&haloL[r3*72 + so];
        acc0 = __builtin_amdgcn_mfma_f32_16x16x32_bf16(ah0, bh, acc0, 0,0,0);
        acc1 = __builtin_amdgcn_mfma_f32_16x16x32_bf16(ah1, bh, acc1, 0,0,0);
        acc2 = __builtin_amdgcn_mfma_f32_16x16x32_bf16(ah2, bh, acc2, 0,0,0);
        acc3 = __builtin_amdgcn_mfma_f32_16x16x32_bf16(ah3, bh, acc3, 0,0,0);
        acc0 = __builtin_amdgcn_mfma_f32_16x16x32_bf16(al0, bh, acc0, 0,0,0);
        acc1 = __builtin_amdgcn_mfma_f32_16x16x32_bf16(al1, bh, acc1, 0,0,0);
        acc2 = __builtin_amdgcn_mfma_f32_16x16x32_bf16(al2, bh, acc2, 0,0,0);
        acc3 = __builtin_amdgcn_mfma_f32_16x16x32_bf16(al3, bh, acc3, 0,0,0);
        acc0 = __builtin_amdgcn_mfma_f32_16x16x32_bf16(ah0, bl, acc0, 0,0,0);
        acc1 = __builtin_amdgcn_mfma_f32_16x16x32_bf16(ah1, bl, acc1, 0,0,0);
        acc2 = __builtin_amdgcn_mfma_f32_16x16x32_bf16(ah2, bl, acc2, 0,0,0);
        acc3 = __builtin_amdgcn_mfma_f32_16x16x32_bf16(ah3, bl, acc3, 0,0,0);
      }
    }
  }
  float bias = Bb[chl];
  int rowb = q*4;
  float* hO = h + (size_t)(offL + nb)*64;
  #pragma unroll
  for (int reg=0;reg<4;++reg){
    int n0 = rowb + reg;
    float v0 = acc0[reg] + bias; if (nb + n0      < N) hO[(size_t)(n0     )*64 + chl] = v0 > 0.f ? v0 : 0.f;
    float v1 = acc1[reg] + bias; if (nb + n0 + 16 < N) hO[(size_t)(n0 + 16)*64 + chl] = v1 > 0.f ? v1 : 0.f;
    float v2 = acc2[reg] + bias; if (nb + n0 + 32 < N) hO[(size_t)(n0 + 32)*64 + chl] = v2 > 0.f ? v2 : 0.f;
    float v3 = acc3[reg] + bias; if (nb + n0 + 48 < N) hO[(size_t)(n0 + 48)*64 + chl] = v3 > 0.f ? v3 : 0.f;
  }
}

// ---------- fused tail: d=4..1, one block (round-7 form) ----------
__global__ __launch_bounds__(256) void k_tail(float* __restrict__ h,
    const float* __restrict__ convW, const float* __restrict__ convB){
  __shared__ float Pt[65][68];
  __shared__ float Wl[64][68];
  int t = threadIdx.x;
  #pragma unroll
  for (int d = 4; d >= 1; --d){
    const int L = d - 1;
    const int Np = 1 << (2*L);
    for (int e = t; e < Np*16; e += 256){
      int node = e >> 4, u = e & 15;
      const float4* c = (const float4*)(h + (size_t)(OFFS[d] + 4*node)*64) + u;
      float4 c0 = c[0], c1 = c[16], c2 = c[32], c3 = c[48];
      float4 pr = *((const float4*)(h + (size_t)(OFFS[L] + node)*64) + u);
      float4 r;
      r.x = 0.25f*(c0.x+c1.x+c2.x+c3.x) + pr.x;
      r.y = 0.25f*(c0.y+c1.y+c2.y+c3.y) + pr.y;
      r.z = 0.25f*(c0.z+c1.z+c2.z+c3.z) + pr.z;
      r.w = 0.25f*(c0.w+c1.w+c2.w+c3.w) + pr.w;
      *(float4*)&Pt[node][u*4] = r;
    }
    if (t < 17) *(float4*)&Pt[64][t*4] = make_float4(0.f,0.f,0.f,0.f);
    __syncthreads();
    if (L == 0){
      if (t < 16) ((float4*)h)[t] = *(const float4*)&Pt[0][t*4];
      break;
    }
    const int R = (L == 3) ? 2 : 1;
    const int res = 1 << L;
    int tr = t >> 3, tc = t & 7;
    bool act = (tr*R) < Np;
    float acc[2][8];
    #pragma unroll
    for (int i=0;i<2;++i)
      #pragma unroll
      for (int c=0;c<8;++c) acc[i][c] = 0.f;
    unsigned ixs[2] = {0,0}, iys[2] = {0,0};
    if (act){
      #pragma unroll
      for (int i=0;i<R;++i){
        unsigned node = (unsigned)(tr*R + i);
        ixs[i] = deint(node); iys[i] = deint(node >> 1);
      }
    }
    const float* WL = convW + (size_t)L*36864;
    float4 rW0, rW1, rW2, rW3;
    {
      const float4* W4 = (const float4*)WL;
      rW0 = W4[t*4]; rW1 = W4[t*4+1]; rW2 = W4[t*4+2]; rW3 = W4[t*4+3];
    }
    for (int m=0;m<9;++m){
      __syncthreads();
      {
        int kk = t >> 2, c0 = (t & 3)*16;
        *(float4*)&Wl[kk][c0]      = rW0;
        *(float4*)&Wl[kk][c0 + 4]  = rW1;
        *(float4*)&Wl[kk][c0 + 8]  = rW2;
        *(float4*)&Wl[kk][c0 + 12] = rW3;
      }
      if (m < 8){
        const float4* W4 = (const float4*)(WL + (size_t)(m+1)*4096);
        rW0 = W4[t*4]; rW1 = W4[t*4+1]; rW2 = W4[t*4+2]; rW3 = W4[t*4+3];
      }
      __syncthreads();
      if (act){
        int dy = m/3 - 1, dx = m%3 - 1;
        int key[2];
        #pragma unroll
        for (int i=0;i<R;++i){
          int nx = (int)ixs[i] + dx, ny = (int)iys[i] + dy;
          key[i] = (nx>=0 && ny>=0 && nx<res && ny<res)
                 ? (int)(ileave((unsigned)nx) | (ileave((unsigned)ny) << 1)) : 64;
        }
        #pragma unroll 2
        for (int k4=0;k4<16;++k4){
          float av4[2][4];
          #pragma unroll
          for (int i=0;i<R;++i){
            float4 aa = *(const float4*)&Pt[key[i]][k4*4];
            av4[i][0]=aa.x; av4[i][1]=aa.y; av4[i][2]=aa.z; av4[i][3]=aa.w;
          }
          #pragma unroll
          for (int j=0;j<4;++j){
            float4 lo = *(const float4*)&Wl[k4*4+j][tc*8];
            float4 hi = *(const float4*)&Wl[k4*4+j][tc*8+4];
            float wv[8];
            wv[0]=lo.x; wv[1]=lo.y; wv[2]=lo.z; wv[3]=lo.w;
            wv[4]=hi.x; wv[5]=hi.y; wv[6]=hi.z; wv[7]=hi.w;
            #pragma unroll
            for (int i=0;i<R;++i){
              float a = av4[i][j];
              #pragma unroll
              for (int c=0;c<8;++c) acc[i][c] += a*wv[c];
            }
          }
        }
      }
    }
    __syncthreads();
    if (act){
      #pragma unroll
      for (int i=0;i<R;++i){
        int node = tr*R + i;
        float ov[8];
        #pragma unroll
        for (int c=0;c<8;++c){
          float v = acc[i][c] + convB[L*64 + tc*8 + c];
          ov[c] = v > 0.f ? v : 0.f;
        }
        float* dst = &h[(size_t)(OFFS[L] + node)*64 + tc*8];
        *(float4*)dst       = *(const float4*)&ov[0];
        *(float4*)(dst + 4) = *(const float4*)&ov[4];
      }
    }
    __syncthreads();
  }
}

// ---------- emb + layernorm + gain (round-7 form) ----------
__global__ __launch_bounds__(256) void k_emb(float* h, const float* __restrict__ embW,
    const float* __restrict__ embB, const float* __restrict__ lng,
    const float* __restrict__ lnb, const float* __restrict__ gain){
  int bb = blockIdx.x;
  int d = 0;
  #pragma unroll
  for (int i = 1; i <= 9; ++i) if (bb >= EBLK[i]) d = i;
  int nb = (bb - EBLK[d]) * 128;
  int N = 1 << (2*d);
  int off = OFFS[d];

  __shared__ float Alt[128][68];
  __shared__ float Wl[64][68];
  int t = threadIdx.x;
  #pragma unroll
  for (int j=0;j<8;++j){
    int e = t + j*256;
    int node = e >> 4, u = e & 15;
    int g = nb + node;
    float4 v = (g < N) ? *((const float4*)(h + (size_t)(off + g)*64) + u)
                       : make_float4(0.f,0.f,0.f,0.f);
    *(float4*)&Alt[node][u*4] = v;
  }
  const float* Wd = embW + (size_t)d*4096;
  for (int idx = t; idx < 4096; idx += 256)
    Wl[idx >> 6][idx & 63] = Wd[idx];
  __syncthreads();
  int tr = t >> 3, tc = t & 7;
  float acc[4][8];
  #pragma unroll
  for (int c=0;c<8;++c){
    float bv = embB[d*64 + tc*8 + c];
    #pragma unroll
    for (int i=0;i<4;++i) acc[i][c] = bv;
  }
  #pragma unroll 2
  for (int k4=0;k4<16;++k4){
    float av4[4][4];
    #pragma unroll
    for (int i=0;i<4;++i){
      float4 aa = *(const float4*)&Alt[tr*4+i][k4*4];
      av4[i][0]=aa.x; av4[i][1]=aa.y; av4[i][2]=aa.z; av4[i][3]=aa.w;
    }
    #pragma unroll
    for (int j=0;j<4;++j){
      float4 lo = *(const float4*)&Wl[k4*4+j][tc*8];
      float4 hi = *(const float4*)&Wl[k4*4+j][tc*8+4];
      float wv[8];
      wv[0]=lo.x; wv[1]=lo.y; wv[2]=lo.z; wv[3]=lo.w;
      wv[4]=hi.x; wv[5]=hi.y; wv[6]=hi.z; wv[7]=hi.w;
      #pragma unroll
      for (int i=0;i<4;++i){
        float a = av4[i][j];
        #pragma unroll
        for (int c=0;c<8;++c) acc[i][c] += a*wv[c];
      }
    }
  }
  float gvals[8], bvals[8];
  #pragma unroll
  for (int c=0;c<8;++c){
    gvals[c] = lng[d*64 + tc*8 + c];
    bvals[c] = lnb[d*64 + tc*8 + c];
  }
  float gn = gain[d];
  #pragma unroll
  for (int i=0;i<4;++i){
    float s = 0.f, q = 0.f;
    #pragma unroll
    for (int c=0;c<8;++c){ s += acc[i][c]; q += acc[i][c]*acc[i][c]; }
    #pragma unroll
    for (int msk = 1; msk < 8; msk <<= 1){
      s += __shfl_xor(s, msk, 64);
      q += __shfl_xor(q, msk, 64);
    }
    float mu = s * 0.015625f;
    float var = q * 0.015625f - mu*mu;
    float rs = rsqrtf(var + 1e-5f);
    int node = nb + tr*4 + i;
    if (node < N){
      float ov[8];
      #pragma unroll
      for (int c=0;c<8;++c)
        ov[c] = ((acc[i][c] - mu) * rs * gvals[c] + bvals[c]) * gn;
      float* dst = &h[(size_t)(off + node)*64 + tc*8];
      *(float4*)dst       = *(const float4*)&ov[0];
      *(float4*)(dst + 4) = *(const float4*)&ov[4];
    }
  }
}

extern "C" void kernel_launch(void* const* d_in, const int* in_sizes, int n_in,
                              void* d_out, int out_size, void* d_ws, size_t ws_size,
                              hipStream_t stream) {
  (void)in_sizes; (void)n_in; (void)out_size;
  const float* feat  = (const float*)d_in[0];
  const float* ipW   = (const float*)d_in[1];
  const float* ipB   = (const float*)d_in[2];
  const float* convW = (const float*)d_in[3];
  const float* convB = (const float*)d_in[4];
  const float* embW  = (const float*)d_in[5];
  const float* embB  = (const float*)d_in[6];
  const float* lng   = (const float*)d_in[7];
  const float* lnb   = (const float*)d_in[8];
  const float* gain  = (const float*)d_in[9];
  float* h = (float*)d_out;

  unsigned short* WH  = (unsigned short*)d_ws;            // 368640 B
  unsigned short* WLo = WH + WFRAG_HALF;                  // 368640 B
  float* hpre = (ws_size >= WFRAG_BYTES + HPRE_BYTES)
              ? (float*)((char*)d_ws + WFRAG_BYTES) : nullptr;

  k_wprep<<<90, 256, 0, stream>>>(convW, WH, WLo);
  k_inproj<<<(TOTAL + 127)/128, 256, 0, stream>>>(feat, ipW, ipB, h, hpre);

  for (int L = 8; L >= 4; --L){
    int Np = 1 << (2*L);
    const float* hPar = hpre ? (hpre + (size_t)(OFFS[L] - OFFS[4])*64)
                             : (h + (size_t)OFFS[L]*64);
    k_conv<<<Np/64, 256, 0, stream>>>(h, hPar,
        WH  + (size_t)(L-4)*36864, WLo + (size_t)(L-4)*36864,
        convB + (size_t)L*64, Np, OFFS[L], OFFS[L+1], L);
  }

  k_tail<<<1, 256, 0, stream>>>(h, convW, convB);
  k_emb<<<2734, 256, 0, stream>>>(h, embW, embB, lng, lnb, gain);
}

// Round 10
// 244.461 us; speedup vs baseline: 2.3436x; 1.0577x over previous
//
#include <hip/hip_runtime.h>
#include <hip/hip_bf16.h>

static constexpr int TOTAL = 349525;
static constexpr int OFFS[11] = {0,1,5,21,85,341,1365,5461,21845,87381,349525};
// emb blocks of 64 nodes per level: counts {1,1,1,1,4,16,64,256,1024,4096}
static constexpr int EB64[11] = {0,1,2,3,4,8,24,88,344,1368,5464};
// conv frags: 8 levels (L=1..8) x 9m x 2ks x 4cb x 64 lanes x 8 bf16
static constexpr size_t CONV_USH = (size_t)8*9*2*4*64*8;    // 294912 ushorts
static constexpr size_t EMB_USH  = (size_t)10*2*4*64*8;     //  40960 ushorts
static constexpr size_t FRAG_USH = CONV_USH + EMB_USH;      // 335872
static constexpr size_t FRAG_BYTES = FRAG_USH*2*2;          // hi+lo = 1343488 B
static constexpr size_t HPRE_BYTES = (size_t)(87381-85)*64*4;

typedef __attribute__((ext_vector_type(8))) short short8;
typedef __attribute__((ext_vector_type(4))) float f32x4;

__device__ __forceinline__ unsigned deint(unsigned v){
  v &= 0x55555555u;
  v = (v | (v>>1)) & 0x33333333u;
  v = (v | (v>>2)) & 0x0F0F0F0Fu;
  v = (v | (v>>4)) & 0x00FF00FFu;
  v = (v | (v>>8)) & 0x0000FFFFu;
  return v;
}
__device__ __forceinline__ unsigned ileave(unsigned v){
  v &= 0xFFFFu;
  v = (v | (v<<8)) & 0x00FF00FFu;
  v = (v | (v<<4)) & 0x0F0F0F0Fu;
  v = (v | (v<<2)) & 0x33333333u;
  v = (v | (v<<1)) & 0x55555555u;
  return v;
}
__device__ __forceinline__ unsigned short f2bh(float x){
  unsigned u = __float_as_uint(x);
  return (unsigned short)((u + 0x7FFFu + ((u>>16)&1u)) >> 16);
}
__device__ __forceinline__ float bh2f(unsigned short h){
  return __uint_as_float(((unsigned)h) << 16);
}
__device__ __forceinline__ void split8(float4 a, float4 b, short8 &hi, short8 &lo){
  float v[8] = {a.x,a.y,a.z,a.w,b.x,b.y,b.z,b.w};
  unsigned short hv[8], lv[8];
  #pragma unroll
  for (int j=0;j<8;++j){ hv[j]=f2bh(v[j]); lv[j]=f2bh(v[j]-bh2f(hv[j])); }
  hi = short8{(short)hv[0],(short)hv[1],(short)hv[2],(short)hv[3],
              (short)hv[4],(short)hv[5],(short)hv[6],(short)hv[7]};
  lo = short8{(short)lv[0],(short)lv[1],(short)lv[2],(short)lv[3],
              (short)lv[4],(short)lv[5],(short)lv[6],(short)lv[7]};
}

// ---------- W prep: conv_W[L=1..8] + emb_W[d=0..9] -> fragment-ordered bf16 hi/lo ----------
__global__ __launch_bounds__(256) void k_wprep(const float* __restrict__ convW,
    const float* __restrict__ embW,
    unsigned short* __restrict__ WH, unsigned short* __restrict__ WLo){
  int tid = blockIdx.x*256 + threadIdx.x;
  if (tid >= 41984) return;
  const float* src;
  size_t dst;
  if (tid < 36864){                       // conv region
    int l=tid&63, cb=(tid>>6)&3, ks=(tid>>8)&1;
    int x=tid>>9; int m=x%9, Lp=x/9;      // L = Lp+1
    int k0=ks*32+((l>>4)<<3), ch=cb*16+(l&15);
    src = convW + (size_t)(Lp+1)*36864 + (size_t)(m*64+k0)*64 + ch;
    dst = (size_t)tid*8;
  } else {                                // emb region
    int t2 = tid - 36864;
    int l=t2&63, cb=(t2>>6)&3, ks=(t2>>8)&1, d=t2>>9;
    int k0=ks*32+((l>>4)<<3), ch=cb*16+(l&15);
    src = embW + (size_t)d*4096 + (size_t)k0*64 + ch;
    dst = CONV_USH + (size_t)t2*8;
  }
  unsigned short hv[8], lv[8];
  #pragma unroll
  for (int j=0;j<8;++j){
    float v = src[(size_t)j*64];
    unsigned short h = f2bh(v);
    hv[j] = h;
    lv[j] = f2bh(v - bh2f(h));
  }
  short8 vh = {(short)hv[0],(short)hv[1],(short)hv[2],(short)hv[3],
               (short)hv[4],(short)hv[5],(short)hv[6],(short)hv[7]};
  short8 vl = {(short)lv[0],(short)lv[1],(short)lv[2],(short)lv[3],
               (short)lv[4],(short)lv[5],(short)lv[6],(short)lv[7]};
  *(short8*)(WH  + dst) = vh;
  *(short8*)(WLo + dst) = vl;
}

// ---------- in_proj (round-7 form + hpre mirror) ----------
__global__ __launch_bounds__(256) void k_inproj(const float* __restrict__ feat,
    const float* __restrict__ W, const float* __restrict__ B,
    float* __restrict__ h, float* __restrict__ hpre){
  __shared__ float Alt[128][44];
  __shared__ float Wl[40][68];
  int t = threadIdx.x;
  int base = blockIdx.x * 128;
  for (int idx = t; idx < 40*64; idx += 256)
    Wl[idx >> 6][idx & 63] = W[idx];
  if (t < 128){
    int g = base + t;
    float* row = Alt[t];
    if (g < TOTAL){
      int d = 0;
      #pragma unroll
      for (int i = 1; i <= 9; ++i) if (g >= OFFS[i]) d = i;
      int local = g - OFFS[d];
      unsigned ix = deint((unsigned)local), iy = deint(((unsigned)local) >> 1);
      float inv = 1.0f / (float)(1 << d);
      float px = ((float)ix + 0.5f) * inv;
      float py = ((float)iy + 0.5f) * inv;
      float pd = (float)d * (1.0f/9.0f);
      row[0] = feat[g]; row[1] = px; row[2] = py; row[3] = pd;
      float p3[3] = {px, py, pd};
      #pragma unroll
      for (int c = 0; c < 3; ++c){
        float s, co;
        __sincosf(6.28318530717958647692f * p3[c], &s, &co);
        float* rb = row + 4 + c*12;
        #pragma unroll
        for (int f = 0; f < 6; ++f){
          rb[f] = s; rb[6+f] = co;
          float s2 = 2.f*s*co, c2 = 1.f - 2.f*s*s;
          s = s2; co = c2;
        }
      }
    } else {
      #pragma unroll
      for (int k = 0; k < 40; ++k) row[k] = 0.f;
    }
  }
  __syncthreads();
  int tr = t >> 3, tc = t & 7;
  float acc[4][8];
  #pragma unroll
  for (int i=0;i<4;++i)
    #pragma unroll
    for (int c=0;c<8;++c) acc[i][c] = 0.f;
  #pragma unroll 2
  for (int k4 = 0; k4 < 10; ++k4){
    float av4[4][4];
    #pragma unroll
    for (int i=0;i<4;++i){
      float4 aa = *(const float4*)&Alt[tr*4+i][k4*4];
      av4[i][0]=aa.x; av4[i][1]=aa.y; av4[i][2]=aa.z; av4[i][3]=aa.w;
    }
    #pragma unroll
    for (int j=0;j<4;++j){
      float4 lo = *(const float4*)&Wl[k4*4+j][tc*8];
      float4 hi = *(const float4*)&Wl[k4*4+j][tc*8+4];
      float wv[8];
      wv[0]=lo.x; wv[1]=lo.y; wv[2]=lo.z; wv[3]=lo.w;
      wv[4]=hi.x; wv[5]=hi.y; wv[6]=hi.z; wv[7]=hi.w;
      #pragma unroll
      for (int i=0;i<4;++i){
        float a = av4[i][j];
        #pragma unroll
        for (int c=0;c<8;++c) acc[i][c] += a*wv[c];
      }
    }
  }
  #pragma unroll
  for (int i=0;i<4;++i){
    int g = base + tr*4 + i;
    if (g >= TOTAL) continue;
    float ov[8];
    #pragma unroll
    for (int c=0;c<8;++c) ov[c] = acc[i][c] + B[tc*8+c];
    float* dst = &h[(size_t)g*64 + tc*8];
    *(float4*)dst       = *(const float4*)&ov[0];
    *(float4*)(dst + 4) = *(const float4*)&ov[4];
    if (hpre && g >= OFFS[4] && g < OFFS[9]){
      float* dp = hpre + (size_t)(g - OFFS[4])*64 + tc*8;
      *(float4*)dp       = *(const float4*)&ov[0];
      *(float4*)(dp + 4) = *(const float4*)&ov[4];
    }
  }
}

// ---------- conv (halo + fused pool + MFMA bf16-split) — round-9 verified ----------
__global__ __launch_bounds__(256) void k_conv(float* __restrict__ h,
    const float* __restrict__ hPar,
    const unsigned short* __restrict__ WHl, const unsigned short* __restrict__ WLl,
    const float* __restrict__ Bb, int N, int offL, int offC, int lbits){
  __shared__ unsigned short haloH[100*72];
  __shared__ unsigned short haloL[100*72];
  __shared__ int hkey[100];
  int t = threadIdx.x;
  int nb = blockIdx.x * 64;
  int res = 1 << lbits;
  if (t < 100){
    int i = t % 10, j = t / 10;
    int gx = (int)deint((unsigned)nb) - 1 + i;
    int gy = (int)deint(((unsigned)nb)>>1) - 1 + j;
    bool ok = (gx>=0 && gy>=0 && gx<res && gy<res);
    hkey[t] = ok ? (int)(ileave((unsigned)gx) | (ileave((unsigned)gy)<<1)) : -1;
  }
  __syncthreads();
  const float* hC = h + (size_t)offC*64;
  for (int e = t; e < 1600; e += 256){
    int hi_ = e >> 4, u = e & 15;
    int key = hkey[hi_];
    float4 r = make_float4(0.f,0.f,0.f,0.f);
    if (key >= 0){
      const float4* c = (const float4*)(hC + (size_t)(4*key)*64) + u;
      float4 c0 = c[0], c1 = c[16], c2 = c[32], c3 = c[48];
      float4 pr = *((const float4*)(hPar + (size_t)key*64) + u);
      r.x = 0.25f*(c0.x+c1.x+c2.x+c3.x) + pr.x;
      r.y = 0.25f*(c0.y+c1.y+c2.y+c3.y) + pr.y;
      r.z = 0.25f*(c0.z+c1.z+c2.z+c3.z) + pr.z;
      r.w = 0.25f*(c0.w+c1.w+c2.w+c3.w) + pr.w;
    }
    unsigned short h0=f2bh(r.x), h1=f2bh(r.y), h2=f2bh(r.z), h3=f2bh(r.w);
    ushort4 rh = make_ushort4(h0,h1,h2,h3);
    ushort4 rl = make_ushort4(f2bh(r.x - bh2f(h0)), f2bh(r.y - bh2f(h1)),
                              f2bh(r.z - bh2f(h2)), f2bh(r.w - bh2f(h3)));
    *(ushort4*)&haloH[hi_*72 + u*4] = rh;
    *(ushort4*)&haloL[hi_*72 + u*4] = rl;
  }
  __syncthreads();

  int cb   = __builtin_amdgcn_readfirstlane((int)(threadIdx.x >> 6));
  int lane = t & 63;
  int q = lane >> 4;
  int chl = cb*16 + (lane & 15);
  int lx0,ly0,lx1,ly1,lx2,ly2,lx3,ly3;
  {
    int n0 = (lane&15), n1 = 16+(lane&15), n2 = 32+(lane&15), n3 = 48+(lane&15);
    lx0=(int)deint((unsigned)n0); ly0=(int)deint(((unsigned)n0)>>1);
    lx1=(int)deint((unsigned)n1); ly1=(int)deint(((unsigned)n1)>>1);
    lx2=(int)deint((unsigned)n2); ly2=(int)deint(((unsigned)n2)>>1);
    lx3=(int)deint((unsigned)n3); ly3=(int)deint(((unsigned)n3)>>1);
  }
  f32x4 acc0 = {0.f,0.f,0.f,0.f}, acc1 = acc0, acc2 = acc0, acc3 = acc0;

  #pragma unroll 1
  for (int dy=0;dy<3;++dy){
    #pragma unroll 1
    for (int dx=0;dx<3;++dx){
      int m = dy*3 + dx;
      int r0 = (ly0+dy)*10 + lx0+dx;
      int r1 = (ly1+dy)*10 + lx1+dx;
      int r2 = (ly2+dy)*10 + lx2+dx;
      int r3 = (ly3+dy)*10 + lx3+dx;
      #pragma unroll
      for (int ks=0;ks<2;++ks){
        const unsigned short* fp = WHl + ((size_t)((m*2+ks)*4 + cb)*64 + lane)*8;
        const unsigned short* fq = WLl + ((size_t)((m*2+ks)*4 + cb)*64 + lane)*8;
        short8 bh = *(const short8*)fp;
        short8 bl = *(const short8*)fq;
        int so = (ks*4 + q)*8;
        short8 ah0 = *(const short8*)&haloH[r0*72 + so];
        short8 al0 = *(const short8*)&haloL[r0*72 + so];
        short8 ah1 = *(const short8*)&haloH[r1*72 + so];
        short8 al1 = *(const short8*)&haloL[r1*72 + so];
        short8 ah2 = *(const short8*)&haloH[r2*72 + so];
        short8 al2 = *(const short8*)&haloL[r2*72 + so];
        short8 ah3 = *(const short8*)&haloH[r3*72 + so];
        short8 al3 = *(const short8*)&haloL[r3*72 + so];
        acc0 = __builtin_amdgcn_mfma_f32_16x16x32_bf16(ah0, bh, acc0, 0,0,0);
        acc1 = __builtin_amdgcn_mfma_f32_16x16x32_bf16(ah1, bh, acc1, 0,0,0);
        acc2 = __builtin_amdgcn_mfma_f32_16x16x32_bf16(ah2, bh, acc2, 0,0,0);
        acc3 = __builtin_amdgcn_mfma_f32_16x16x32_bf16(ah3, bh, acc3, 0,0,0);
        acc0 = __builtin_amdgcn_mfma_f32_16x16x32_bf16(al0, bh, acc0, 0,0,0);
        acc1 = __builtin_amdgcn_mfma_f32_16x16x32_bf16(al1, bh, acc1, 0,0,0);
        acc2 = __builtin_amdgcn_mfma_f32_16x16x32_bf16(al2, bh, acc2, 0,0,0);
        acc3 = __builtin_amdgcn_mfma_f32_16x16x32_bf16(al3, bh, acc3, 0,0,0);
        acc0 = __builtin_amdgcn_mfma_f32_16x16x32_bf16(ah0, bl, acc0, 0,0,0);
        acc1 = __builtin_amdgcn_mfma_f32_16x16x32_bf16(ah1, bl, acc1, 0,0,0);
        acc2 = __builtin_amdgcn_mfma_f32_16x16x32_bf16(ah2, bl, acc2, 0,0,0);
        acc3 = __builtin_amdgcn_mfma_f32_16x16x32_bf16(ah3, bl, acc3, 0,0,0);
      }
    }
  }
  float bias = Bb[chl];
  int rowb = q*4;
  float* hO = h + (size_t)(offL + nb)*64;
  #pragma unroll
  for (int reg=0;reg<4;++reg){
    int n0 = rowb + reg;
    float v0 = acc0[reg] + bias; if (nb + n0      < N) hO[(size_t)(n0     )*64 + chl] = v0 > 0.f ? v0 : 0.f;
    float v1 = acc1[reg] + bias; if (nb + n0 + 16 < N) hO[(size_t)(n0 + 16)*64 + chl] = v1 > 0.f ? v1 : 0.f;
    float v2 = acc2[reg] + bias; if (nb + n0 + 32 < N) hO[(size_t)(n0 + 32)*64 + chl] = v2 > 0.f ? v2 : 0.f;
    float v3 = acc3[reg] + bias; if (nb + n0 + 48 < N) hO[(size_t)(n0 + 48)*64 + chl] = v3 > 0.f ? v3 : 0.f;
  }
}

// ---------- tail level L (MFMA): pool -> Pt LDS (bf16 hi/lo), barrier-free m-loop ----------
template<int L>
__device__ __forceinline__ void tail_level(float* __restrict__ h,
    const unsigned short* __restrict__ WHc, const unsigned short* __restrict__ WLc,
    const float* __restrict__ convB,
    unsigned short* __restrict__ PtH, unsigned short* __restrict__ PtL, int t){
  constexpr int Np = 1 << (2*L);
  constexpr int NT = (Np + 15)/16;     // 4,1,1
  constexpr int res = 1 << L;
  // stage pooled rows (zero rows >= Np and row 64)
  for (int e = t; e < 65*16; e += 256){
    int node = e >> 4, u = e & 15;
    float4 r = make_float4(0.f,0.f,0.f,0.f);
    if (node < Np){
      const float4* c = (const float4*)(h + (size_t)(OFFS[L+1] + 4*node)*64) + u;
      float4 c0 = c[0], c1 = c[16], c2 = c[32], c3 = c[48];
      float4 pr = *((const float4*)(h + (size_t)(OFFS[L] + node)*64) + u);
      r.x = 0.25f*(c0.x+c1.x+c2.x+c3.x) + pr.x;
      r.y = 0.25f*(c0.y+c1.y+c2.y+c3.y) + pr.y;
      r.z = 0.25f*(c0.z+c1.z+c2.z+c3.z) + pr.z;
      r.w = 0.25f*(c0.w+c1.w+c2.w+c3.w) + pr.w;
    }
    unsigned short h0=f2bh(r.x), h1=f2bh(r.y), h2=f2bh(r.z), h3=f2bh(r.w);
    *(ushort4*)&PtH[node*72 + u*4] = make_ushort4(h0,h1,h2,h3);
    *(ushort4*)&PtL[node*72 + u*4] = make_ushort4(
        f2bh(r.x - bh2f(h0)), f2bh(r.y - bh2f(h1)),
        f2bh(r.z - bh2f(h2)), f2bh(r.w - bh2f(h3)));
  }
  __syncthreads();
  int cb = __builtin_amdgcn_readfirstlane(t >> 6);
  int lane = t & 63;
  int q = lane >> 4;
  int chl = cb*16 + (lane & 15);
  int lx[NT], ly[NT];
  #pragma unroll
  for (int i=0;i<NT;++i){
    unsigned n = (unsigned)(i*16 + (lane & 15));
    lx[i] = (int)deint(n); ly[i] = (int)deint(n >> 1);
  }
  f32x4 acc[NT];
  #pragma unroll
  for (int i=0;i<NT;++i) acc[i] = f32x4{0.f,0.f,0.f,0.f};
  #pragma unroll 1
  for (int m=0;m<9;++m){
    int dy = m/3 - 1, dx = m%3 - 1;
    size_t f0 = ((size_t)((m*2+0)*4 + cb)*64 + lane)*8;
    size_t f1 = ((size_t)((m*2+1)*4 + cb)*64 + lane)*8;
    short8 bh0 = *(const short8*)(WHc + f0);
    short8 bl0 = *(const short8*)(WLc + f0);
    short8 bh1 = *(const short8*)(WHc + f1);
    short8 bl1 = *(const short8*)(WLc + f1);
    #pragma unroll
    for (int i=0;i<NT;++i){
      int nx = lx[i]+dx, ny = ly[i]+dy;
      int key = (nx>=0 && ny>=0 && nx<res && ny<res)
              ? (int)(ileave((unsigned)nx) | (ileave((unsigned)ny)<<1)) : 64;
      const unsigned short* pH = PtH + key*72;
      const unsigned short* pL = PtL + key*72;
      short8 ah0 = *(const short8*)(pH + q*8);
      short8 al0 = *(const short8*)(pL + q*8);
      short8 ah1 = *(const short8*)(pH + 32 + q*8);
      short8 al1 = *(const short8*)(pL + 32 + q*8);
      acc[i] = __builtin_amdgcn_mfma_f32_16x16x32_bf16(ah0, bh0, acc[i], 0,0,0);
      acc[i] = __builtin_amdgcn_mfma_f32_16x16x32_bf16(al0, bh0, acc[i], 0,0,0);
      acc[i] = __builtin_amdgcn_mfma_f32_16x16x32_bf16(ah0, bl0, acc[i], 0,0,0);
      acc[i] = __builtin_amdgcn_mfma_f32_16x16x32_bf16(ah1, bh1, acc[i], 0,0,0);
      acc[i] = __builtin_amdgcn_mfma_f32_16x16x32_bf16(al1, bh1, acc[i], 0,0,0);
      acc[i] = __builtin_amdgcn_mfma_f32_16x16x32_bf16(ah1, bl1, acc[i], 0,0,0);
    }
  }
  float bias = convB[L*64 + chl];
  #pragma unroll
  for (int i=0;i<NT;++i){
    #pragma unroll
    for (int reg=0;reg<4;++reg){
      int ni = i*16 + q*4 + reg;
      if (ni < Np){
        float v = acc[i][reg] + bias;
        h[(size_t)(OFFS[L] + ni)*64 + chl] = v > 0.f ? v : 0.f;
      }
    }
  }
  __syncthreads();   // h writes visible + Pt reads done before next level restages
}

__global__ __launch_bounds__(256) void k_tail(float* __restrict__ h,
    const unsigned short* __restrict__ WH, const unsigned short* __restrict__ WLo,
    const float* __restrict__ convB){
  __shared__ unsigned short PtH[65*72];
  __shared__ unsigned short PtL[65*72];
  int t = threadIdx.x;
  tail_level<3>(h, WH + (size_t)2*36864, WLo + (size_t)2*36864, convB, PtH, PtL, t);
  tail_level<2>(h, WH + (size_t)1*36864, WLo + (size_t)1*36864, convB, PtH, PtL, t);
  tail_level<1>(h, WH,                   WLo,                   convB, PtH, PtL, t);
  // final L=0: h[0] += mean(children h[1..4])
  if (t < 16){
    const float4* c = (const float4*)(h + (size_t)OFFS[1]*64) + t;
    float4 c0 = c[0], c1 = c[16], c2 = c[32], c3 = c[48];
    float4 pr = ((const float4*)h)[t];
    float4 r;
    r.x = 0.25f*(c0.x+c1.x+c2.x+c3.x) + pr.x;
    r.y = 0.25f*(c0.y+c1.y+c2.y+c3.y) + pr.y;
    r.z = 0.25f*(c0.z+c1.z+c2.z+c3.z) + pr.z;
    r.w = 0.25f*(c0.w+c1.w+c2.w+c3.w) + pr.w;
    ((float4*)h)[t] = r;
  }
}

// ---------- emb + LN (MFMA, A direct from global, frag W) ----------
__global__ __launch_bounds__(256) void k_emb(float* __restrict__ h,
    const unsigned short* __restrict__ EH, const unsigned short* __restrict__ ELo,
    const float* __restrict__ embB, const float* __restrict__ lng,
    const float* __restrict__ lnb, const float* __restrict__ gain){
  __shared__ float sq[64][4];
  __shared__ float qq[64][4];
  __shared__ float mr[64][2];
  int bb = blockIdx.x;
  int d = 0;
  #pragma unroll
  for (int i=1;i<=9;++i) if (bb >= EB64[i]) d = i;
  int nb = (bb - EB64[d]) * 64;
  int N = 1 << (2*d);
  int off = OFFS[d];
  int t = threadIdx.x;
  int cb = __builtin_amdgcn_readfirstlane(t >> 6);
  int lane = t & 63;
  int q = lane >> 4;
  int chl = cb*16 + (lane & 15);

  size_t f0 = (((size_t)(d*2+0)*4 + cb)*64 + lane)*8;
  size_t f1 = (((size_t)(d*2+1)*4 + cb)*64 + lane)*8;
  short8 bh0 = *(const short8*)(EH + f0);
  short8 bl0 = *(const short8*)(ELo + f0);
  short8 bh1 = *(const short8*)(EH + f1);
  short8 bl1 = *(const short8*)(ELo + f1);

  const float* hb = h + ((size_t)off + nb)*64;
  f32x4 acc[4];
  #pragma unroll
  for (int i=0;i<4;++i) acc[i] = f32x4{0.f,0.f,0.f,0.f};
  #pragma unroll
  for (int i=0;i<4;++i){
    const float* rp = hb + (size_t)(i*16 + (lane & 15))*64 + q*8;
    float4 a0 = *(const float4*)rp;
    float4 a1 = *(const float4*)(rp + 4);
    float4 a2 = *(const float4*)(rp + 32);
    float4 a3 = *(const float4*)(rp + 36);
    short8 ah0, al0, ah1, al1;
    split8(a0, a1, ah0, al0);
    split8(a2, a3, ah1, al1);
    acc[i] = __builtin_amdgcn_mfma_f32_16x16x32_bf16(ah0, bh0, acc[i], 0,0,0);
    acc[i] = __builtin_amdgcn_mfma_f32_16x16x32_bf16(al0, bh0, acc[i], 0,0,0);
    acc[i] = __builtin_amdgcn_mfma_f32_16x16x32_bf16(ah0, bl0, acc[i], 0,0,0);
    acc[i] = __builtin_amdgcn_mfma_f32_16x16x32_bf16(ah1, bh1, acc[i], 0,0,0);
    acc[i] = __builtin_amdgcn_mfma_f32_16x16x32_bf16(al1, bh1, acc[i], 0,0,0);
    acc[i] = __builtin_amdgcn_mfma_f32_16x16x32_bf16(ah1, bl1, acc[i], 0,0,0);
  }
  float bias = embB[d*64 + chl];
  float z[4][4];
  #pragma unroll
  for (int i=0;i<4;++i){
    #pragma unroll
    for (int r=0;r<4;++r){
      float v = acc[i][r] + bias;
      z[i][r] = v;
      float s = v, qv = v*v;
      #pragma unroll
      for (int mk=1; mk<16; mk<<=1){
        s  += __shfl_xor(s, mk, 64);
        qv += __shfl_xor(qv, mk, 64);
      }
      if ((lane & 15) == 0){
        int ni = i*16 + q*4 + r;
        sq[ni][cb] = s; qq[ni][cb] = qv;
      }
    }
  }
  __syncthreads();
  if (t < 64){
    float S = sq[t][0]+sq[t][1]+sq[t][2]+sq[t][3];
    float Q = qq[t][0]+qq[t][1]+qq[t][2]+qq[t][3];
    float mu = S * 0.015625f;
    float var = Q * 0.015625f - mu*mu;
    mr[t][0] = mu; mr[t][1] = rsqrtf(var + 1e-5f);
  }
  __syncthreads();
  float gch = lng[d*64 + chl], bch = lnb[d*64 + chl], gn = gain[d];
  #pragma unroll
  for (int i=0;i<4;++i){
    #pragma unroll
    for (int r=0;r<4;++r){
      int ni = i*16 + q*4 + r;
      if (nb + ni < N){
        float mu = mr[ni][0], rs = mr[ni][1];
        h[((size_t)off + nb + ni)*64 + chl] = ((z[i][r] - mu)*rs*gch + bch)*gn;
      }
    }
  }
}

extern "C" void kernel_launch(void* const* d_in, const int* in_sizes, int n_in,
                              void* d_out, int out_size, void* d_ws, size_t ws_size,
                              hipStream_t stream) {
  (void)in_sizes; (void)n_in; (void)out_size;
  const float* feat  = (const float*)d_in[0];
  const float* ipW   = (const float*)d_in[1];
  const float* ipB   = (const float*)d_in[2];
  const float* convW = (const float*)d_in[3];
  const float* convB = (const float*)d_in[4];
  const float* embW  = (const float*)d_in[5];
  const float* embB  = (const float*)d_in[6];
  const float* lng   = (const float*)d_in[7];
  const float* lnb   = (const float*)d_in[8];
  const float* gain  = (const float*)d_in[9];
  float* h = (float*)d_out;

  unsigned short* WH  = (unsigned short*)d_ws;
  unsigned short* WLo = WH + FRAG_USH;
  float* hpre = (ws_size >= FRAG_BYTES + HPRE_BYTES)
              ? (float*)((char*)d_ws + FRAG_BYTES) : nullptr;

  k_wprep<<<164, 256, 0, stream>>>(convW, embW, WH, WLo);
  k_inproj<<<(TOTAL + 127)/128, 256, 0, stream>>>(feat, ipW, ipB, h, hpre);

  for (int L = 8; L >= 4; --L){
    int Np = 1 << (2*L);
    const float* hPar = hpre ? (hpre + (size_t)(OFFS[L] - OFFS[4])*64)
                             : (h + (size_t)OFFS[L]*64);
    k_conv<<<Np/64, 256, 0, stream>>>(h, hPar,
        WH  + (size_t)(L-1)*36864, WLo + (size_t)(L-1)*36864,
        convB + (size_t)L*64, Np, OFFS[L], OFFS[L+1], L);
  }

  k_tail<<<1, 256, 0, stream>>>(h, WH, WLo, convB);
  k_emb<<<5464, 256, 0, stream>>>(h, WH + CONV_USH, WLo + CONV_USH,
                                  embB, lng, lnb, gain);
}

// Round 11
// 221.921 us; speedup vs baseline: 2.5816x; 1.1016x over previous
//
#include <hip/hip_runtime.h>
#include <hip/hip_bf16.h>

static constexpr int TOTAL = 349525;
static constexpr int OFFS[11] = {0,1,5,21,85,341,1365,5461,21845,87381,349525};
// emb blocks of 64 nodes per level: counts {1,1,1,1,4,16,64,256,1024,4096}
static constexpr int EB64[11] = {0,1,2,3,4,8,24,88,344,1368,5464};
// conv frags: 8 levels (L=1..8) x 9m x 2ks x 4cb x 64 lanes x 8 bf16
static constexpr size_t CONV_USH = (size_t)8*9*2*4*64*8;    // 294912 ushorts
static constexpr size_t EMB_USH  = (size_t)10*2*4*64*8;     //  40960 ushorts
static constexpr size_t FRAG_USH = CONV_USH + EMB_USH;      // 335872
static constexpr size_t FRAG_BYTES = FRAG_USH*2*2;          // hi+lo = 1343488 B
static constexpr size_t HPRE_BYTES = (size_t)(87381-85)*64*4;

typedef __attribute__((ext_vector_type(8))) short short8;
typedef __attribute__((ext_vector_type(4))) float f32x4;

__device__ __forceinline__ unsigned deint(unsigned v){
  v &= 0x55555555u;
  v = (v | (v>>1)) & 0x33333333u;
  v = (v | (v>>2)) & 0x0F0F0F0Fu;
  v = (v | (v>>4)) & 0x00FF00FFu;
  v = (v | (v>>8)) & 0x0000FFFFu;
  return v;
}
__device__ __forceinline__ unsigned ileave(unsigned v){
  v &= 0xFFFFu;
  v = (v | (v<<8)) & 0x00FF00FFu;
  v = (v | (v<<4)) & 0x0F0F0F0Fu;
  v = (v | (v<<2)) & 0x33333333u;
  v = (v | (v<<1)) & 0x55555555u;
  return v;
}
__device__ __forceinline__ unsigned short f2bh(float x){
  unsigned u = __float_as_uint(x);
  return (unsigned short)((u + 0x7FFFu + ((u>>16)&1u)) >> 16);
}
__device__ __forceinline__ float bh2f(unsigned short h){
  return __uint_as_float(((unsigned)h) << 16);
}
__device__ __forceinline__ void split8(float4 a, float4 b, short8 &hi, short8 &lo){
  float v[8] = {a.x,a.y,a.z,a.w,b.x,b.y,b.z,b.w};
  unsigned short hv[8], lv[8];
  #pragma unroll
  for (int j=0;j<8;++j){ hv[j]=f2bh(v[j]); lv[j]=f2bh(v[j]-bh2f(hv[j])); }
  hi = short8{(short)hv[0],(short)hv[1],(short)hv[2],(short)hv[3],
              (short)hv[4],(short)hv[5],(short)hv[6],(short)hv[7]};
  lo = short8{(short)lv[0],(short)lv[1],(short)lv[2],(short)lv[3],
              (short)lv[4],(short)lv[5],(short)lv[6],(short)lv[7]};
}

// ---------- W prep: conv_W[L=1..8] + emb_W[d=0..9] -> fragment-ordered bf16 hi/lo ----------
__global__ __launch_bounds__(256) void k_wprep(const float* __restrict__ convW,
    const float* __restrict__ embW,
    unsigned short* __restrict__ WH, unsigned short* __restrict__ WLo){
  int tid = blockIdx.x*256 + threadIdx.x;
  if (tid >= 41984) return;
  const float* src;
  size_t dst;
  if (tid < 36864){                       // conv region
    int l=tid&63, cb=(tid>>6)&3, ks=(tid>>8)&1;
    int x=tid>>9; int m=x%9, Lp=x/9;      // L = Lp+1
    int k0=ks*32+((l>>4)<<3), ch=cb*16+(l&15);
    src = convW + (size_t)(Lp+1)*36864 + (size_t)(m*64+k0)*64 + ch;
    dst = (size_t)tid*8;
  } else {                                // emb region
    int t2 = tid - 36864;
    int l=t2&63, cb=(t2>>6)&3, ks=(t2>>8)&1, d=t2>>9;
    int k0=ks*32+((l>>4)<<3), ch=cb*16+(l&15);
    src = embW + (size_t)d*4096 + (size_t)k0*64 + ch;
    dst = CONV_USH + (size_t)t2*8;
  }
  unsigned short hv[8], lv[8];
  #pragma unroll
  for (int j=0;j<8;++j){
    float v = src[(size_t)j*64];
    unsigned short h = f2bh(v);
    hv[j] = h;
    lv[j] = f2bh(v - bh2f(h));
  }
  short8 vh = {(short)hv[0],(short)hv[1],(short)hv[2],(short)hv[3],
               (short)hv[4],(short)hv[5],(short)hv[6],(short)hv[7]};
  short8 vl = {(short)lv[0],(short)lv[1],(short)lv[2],(short)lv[3],
               (short)lv[4],(short)lv[5],(short)lv[6],(short)lv[7]};
  *(short8*)(WH  + dst) = vh;
  *(short8*)(WLo + dst) = vl;
}

// ---------- in_proj (round-7 form + hpre mirror) ----------
__global__ __launch_bounds__(256) void k_inproj(const float* __restrict__ feat,
    const float* __restrict__ W, const float* __restrict__ B,
    float* __restrict__ h, float* __restrict__ hpre){
  __shared__ float Alt[128][44];
  __shared__ float Wl[40][68];
  int t = threadIdx.x;
  int base = blockIdx.x * 128;
  for (int idx = t; idx < 40*64; idx += 256)
    Wl[idx >> 6][idx & 63] = W[idx];
  if (t < 128){
    int g = base + t;
    float* row = Alt[t];
    if (g < TOTAL){
      int d = 0;
      #pragma unroll
      for (int i = 1; i <= 9; ++i) if (g >= OFFS[i]) d = i;
      int local = g - OFFS[d];
      unsigned ix = deint((unsigned)local), iy = deint(((unsigned)local) >> 1);
      float inv = 1.0f / (float)(1 << d);
      float px = ((float)ix + 0.5f) * inv;
      float py = ((float)iy + 0.5f) * inv;
      float pd = (float)d * (1.0f/9.0f);
      row[0] = feat[g]; row[1] = px; row[2] = py; row[3] = pd;
      float p3[3] = {px, py, pd};
      #pragma unroll
      for (int c = 0; c < 3; ++c){
        float s, co;
        __sincosf(6.28318530717958647692f * p3[c], &s, &co);
        float* rb = row + 4 + c*12;
        #pragma unroll
        for (int f = 0; f < 6; ++f){
          rb[f] = s; rb[6+f] = co;
          float s2 = 2.f*s*co, c2 = 1.f - 2.f*s*s;
          s = s2; co = c2;
        }
      }
    } else {
      #pragma unroll
      for (int k = 0; k < 40; ++k) row[k] = 0.f;
    }
  }
  __syncthreads();
  int tr = t >> 3, tc = t & 7;
  float acc[4][8];
  #pragma unroll
  for (int i=0;i<4;++i)
    #pragma unroll
    for (int c=0;c<8;++c) acc[i][c] = 0.f;
  #pragma unroll 2
  for (int k4 = 0; k4 < 10; ++k4){
    float av4[4][4];
    #pragma unroll
    for (int i=0;i<4;++i){
      float4 aa = *(const float4*)&Alt[tr*4+i][k4*4];
      av4[i][0]=aa.x; av4[i][1]=aa.y; av4[i][2]=aa.z; av4[i][3]=aa.w;
    }
    #pragma unroll
    for (int j=0;j<4;++j){
      float4 lo = *(const float4*)&Wl[k4*4+j][tc*8];
      float4 hi = *(const float4*)&Wl[k4*4+j][tc*8+4];
      float wv[8];
      wv[0]=lo.x; wv[1]=lo.y; wv[2]=lo.z; wv[3]=lo.w;
      wv[4]=hi.x; wv[5]=hi.y; wv[6]=hi.z; wv[7]=hi.w;
      #pragma unroll
      for (int i=0;i<4;++i){
        float a = av4[i][j];
        #pragma unroll
        for (int c=0;c<8;++c) acc[i][c] += a*wv[c];
      }
    }
  }
  #pragma unroll
  for (int i=0;i<4;++i){
    int g = base + tr*4 + i;
    if (g >= TOTAL) continue;
    float ov[8];
    #pragma unroll
    for (int c=0;c<8;++c) ov[c] = acc[i][c] + B[tc*8+c];
    float* dst = &h[(size_t)g*64 + tc*8];
    *(float4*)dst       = *(const float4*)&ov[0];
    *(float4*)(dst + 4) = *(const float4*)&ov[4];
    if (hpre && g >= OFFS[4] && g < OFFS[9]){
      float* dp = hpre + (size_t)(g - OFFS[4])*64 + tc*8;
      *(float4*)dp       = *(const float4*)&ov[0];
      *(float4*)(dp + 4) = *(const float4*)&ov[4];
    }
  }
}

// ---------- conv (halo + fused pool + MFMA bf16-split) — verified ----------
__global__ __launch_bounds__(256) void k_conv(float* __restrict__ h,
    const float* __restrict__ hPar,
    const unsigned short* __restrict__ WHl, const unsigned short* __restrict__ WLl,
    const float* __restrict__ Bb, int N, int offL, int offC, int lbits){
  __shared__ unsigned short haloH[100*72];
  __shared__ unsigned short haloL[100*72];
  __shared__ int hkey[100];
  int t = threadIdx.x;
  int nb = blockIdx.x * 64;
  int res = 1 << lbits;
  if (t < 100){
    int i = t % 10, j = t / 10;
    int gx = (int)deint((unsigned)nb) - 1 + i;
    int gy = (int)deint(((unsigned)nb)>>1) - 1 + j;
    bool ok = (gx>=0 && gy>=0 && gx<res && gy<res);
    hkey[t] = ok ? (int)(ileave((unsigned)gx) | (ileave((unsigned)gy)<<1)) : -1;
  }
  __syncthreads();
  const float* hC = h + (size_t)offC*64;
  for (int e = t; e < 1600; e += 256){
    int hi_ = e >> 4, u = e & 15;
    int key = hkey[hi_];
    float4 r = make_float4(0.f,0.f,0.f,0.f);
    if (key >= 0){
      const float4* c = (const float4*)(hC + (size_t)(4*key)*64) + u;
      float4 c0 = c[0], c1 = c[16], c2 = c[32], c3 = c[48];
      float4 pr = *((const float4*)(hPar + (size_t)key*64) + u);
      r.x = 0.25f*(c0.x+c1.x+c2.x+c3.x) + pr.x;
      r.y = 0.25f*(c0.y+c1.y+c2.y+c3.y) + pr.y;
      r.z = 0.25f*(c0.z+c1.z+c2.z+c3.z) + pr.z;
      r.w = 0.25f*(c0.w+c1.w+c2.w+c3.w) + pr.w;
    }
    unsigned short h0=f2bh(r.x), h1=f2bh(r.y), h2=f2bh(r.z), h3=f2bh(r.w);
    ushort4 rh = make_ushort4(h0,h1,h2,h3);
    ushort4 rl = make_ushort4(f2bh(r.x - bh2f(h0)), f2bh(r.y - bh2f(h1)),
                              f2bh(r.z - bh2f(h2)), f2bh(r.w - bh2f(h3)));
    *(ushort4*)&haloH[hi_*72 + u*4] = rh;
    *(ushort4*)&haloL[hi_*72 + u*4] = rl;
  }
  __syncthreads();

  int cb   = __builtin_amdgcn_readfirstlane((int)(threadIdx.x >> 6));
  int lane = t & 63;
  int q = lane >> 4;
  int chl = cb*16 + (lane & 15);
  int lx0,ly0,lx1,ly1,lx2,ly2,lx3,ly3;
  {
    int n0 = (lane&15), n1 = 16+(lane&15), n2 = 32+(lane&15), n3 = 48+(lane&15);
    lx0=(int)deint((unsigned)n0); ly0=(int)deint(((unsigned)n0)>>1);
    lx1=(int)deint((unsigned)n1); ly1=(int)deint(((unsigned)n1)>>1);
    lx2=(int)deint((unsigned)n2); ly2=(int)deint(((unsigned)n2)>>1);
    lx3=(int)deint((unsigned)n3); ly3=(int)deint(((unsigned)n3)>>1);
  }
  f32x4 acc0 = {0.f,0.f,0.f,0.f}, acc1 = acc0, acc2 = acc0, acc3 = acc0;

  #pragma unroll 1
  for (int dy=0;dy<3;++dy){
    #pragma unroll 1
    for (int dx=0;dx<3;++dx){
      int m = dy*3 + dx;
      int r0 = (ly0+dy)*10 + lx0+dx;
      int r1 = (ly1+dy)*10 + lx1+dx;
      int r2 = (ly2+dy)*10 + lx2+dx;
      int r3 = (ly3+dy)*10 + lx3+dx;
      #pragma unroll
      for (int ks=0;ks<2;++ks){
        const unsigned short* fp = WHl + ((size_t)((m*2+ks)*4 + cb)*64 + lane)*8;
        const unsigned short* fq = WLl + ((size_t)((m*2+ks)*4 + cb)*64 + lane)*8;
        short8 bh = *(const short8*)fp;
        short8 bl = *(const short8*)fq;
        int so = (ks*4 + q)*8;
        short8 ah0 = *(const short8*)&haloH[r0*72 + so];
        short8 al0 = *(const short8*)&haloL[r0*72 + so];
        short8 ah1 = *(const short8*)&haloH[r1*72 + so];
        short8 al1 = *(const short8*)&haloL[r1*72 + so];
        short8 ah2 = *(const short8*)&haloH[r2*72 + so];
        short8 al2 = *(const short8*)&haloL[r2*72 + so];
        short8 ah3 = *(const short8*)&haloH[r3*72 + so];
        short8 al3 = *(const short8*)&haloL[r3*72 + so];
        acc0 = __builtin_amdgcn_mfma_f32_16x16x32_bf16(ah0, bh, acc0, 0,0,0);
        acc1 = __builtin_amdgcn_mfma_f32_16x16x32_bf16(ah1, bh, acc1, 0,0,0);
        acc2 = __builtin_amdgcn_mfma_f32_16x16x32_bf16(ah2, bh, acc2, 0,0,0);
        acc3 = __builtin_amdgcn_mfma_f32_16x16x32_bf16(ah3, bh, acc3, 0,0,0);
        acc0 = __builtin_amdgcn_mfma_f32_16x16x32_bf16(al0, bh, acc0, 0,0,0);
        acc1 = __builtin_amdgcn_mfma_f32_16x16x32_bf16(al1, bh, acc1, 0,0,0);
        acc2 = __builtin_amdgcn_mfma_f32_16x16x32_bf16(al2, bh, acc2, 0,0,0);
        acc3 = __builtin_amdgcn_mfma_f32_16x16x32_bf16(al3, bh, acc3, 0,0,0);
        acc0 = __builtin_amdgcn_mfma_f32_16x16x32_bf16(ah0, bl, acc0, 0,0,0);
        acc1 = __builtin_amdgcn_mfma_f32_16x16x32_bf16(ah1, bl, acc1, 0,0,0);
        acc2 = __builtin_amdgcn_mfma_f32_16x16x32_bf16(ah2, bl, acc2, 0,0,0);
        acc3 = __builtin_amdgcn_mfma_f32_16x16x32_bf16(ah3, bl, acc3, 0,0,0);
      }
    }
  }
  float bias = Bb[chl];
  int rowb = q*4;
  float* hO = h + (size_t)(offL + nb)*64;
  #pragma unroll
  for (int reg=0;reg<4;++reg){
    int n0 = rowb + reg;
    float v0 = acc0[reg] + bias; if (nb + n0      < N) hO[(size_t)(n0     )*64 + chl] = v0 > 0.f ? v0 : 0.f;
    float v1 = acc1[reg] + bias; if (nb + n0 + 16 < N) hO[(size_t)(n0 + 16)*64 + chl] = v1 > 0.f ? v1 : 0.f;
    float v2 = acc2[reg] + bias; if (nb + n0 + 32 < N) hO[(size_t)(n0 + 32)*64 + chl] = v2 > 0.f ? v2 : 0.f;
    float v3 = acc3[reg] + bias; if (nb + n0 + 48 < N) hO[(size_t)(n0 + 48)*64 + chl] = v3 > 0.f ? v3 : 0.f;
  }
}

// ---------- tail level L (MFMA): pool -> Pt LDS (bf16 hi/lo), barrier-free m-loop ----------
template<int L>
__device__ __forceinline__ void tail_level(float* __restrict__ h,
    const unsigned short* __restrict__ WHc, const unsigned short* __restrict__ WLc,
    const float* __restrict__ convB,
    unsigned short* __restrict__ PtH, unsigned short* __restrict__ PtL, int t){
  constexpr int Np = 1 << (2*L);
  constexpr int NT = (Np + 15)/16;     // 16,4,1,1
  constexpr int res = 1 << L;
  // stage pooled rows; row Np = zero row for invalid neighbors
  for (int e = t; e < (Np+1)*16; e += 256){
    int node = e >> 4, u = e & 15;
    float4 r = make_float4(0.f,0.f,0.f,0.f);
    if (node < Np){
      const float4* c = (const float4*)(h + (size_t)(OFFS[L+1] + 4*node)*64) + u;
      float4 c0 = c[0], c1 = c[16], c2 = c[32], c3 = c[48];
      float4 pr = *((const float4*)(h + (size_t)(OFFS[L] + node)*64) + u);
      r.x = 0.25f*(c0.x+c1.x+c2.x+c3.x) + pr.x;
      r.y = 0.25f*(c0.y+c1.y+c2.y+c3.y) + pr.y;
      r.z = 0.25f*(c0.z+c1.z+c2.z+c3.z) + pr.z;
      r.w = 0.25f*(c0.w+c1.w+c2.w+c3.w) + pr.w;
    }
    unsigned short h0=f2bh(r.x), h1=f2bh(r.y), h2=f2bh(r.z), h3=f2bh(r.w);
    *(ushort4*)&PtH[node*72 + u*4] = make_ushort4(h0,h1,h2,h3);
    *(ushort4*)&PtL[node*72 + u*4] = make_ushort4(
        f2bh(r.x - bh2f(h0)), f2bh(r.y - bh2f(h1)),
        f2bh(r.z - bh2f(h2)), f2bh(r.w - bh2f(h3)));
  }
  __syncthreads();
  int cb = __builtin_amdgcn_readfirstlane(t >> 6);
  int lane = t & 63;
  int q = lane >> 4;
  int chl = cb*16 + (lane & 15);
  int lx[NT], ly[NT];
  #pragma unroll
  for (int i=0;i<NT;++i){
    unsigned n = (unsigned)(i*16 + (lane & 15));
    lx[i] = (int)deint(n); ly[i] = (int)deint(n >> 1);
  }
  f32x4 acc[NT];
  #pragma unroll
  for (int i=0;i<NT;++i) acc[i] = f32x4{0.f,0.f,0.f,0.f};
  #pragma unroll 1
  for (int m=0;m<9;++m){
    int dy = m/3 - 1, dx = m%3 - 1;
    size_t f0 = ((size_t)((m*2+0)*4 + cb)*64 + lane)*8;
    size_t f1 = ((size_t)((m*2+1)*4 + cb)*64 + lane)*8;
    short8 bh0 = *(const short8*)(WHc + f0);
    short8 bl0 = *(const short8*)(WLc + f0);
    short8 bh1 = *(const short8*)(WHc + f1);
    short8 bl1 = *(const short8*)(WLc + f1);
    #pragma unroll
    for (int i=0;i<NT;++i){
      int nx = lx[i]+dx, ny = ly[i]+dy;
      int key = (nx>=0 && ny>=0 && nx<res && ny<res)
              ? (int)(ileave((unsigned)nx) | (ileave((unsigned)ny)<<1)) : Np;
      const unsigned short* pH = PtH + key*72;
      const unsigned short* pL = PtL + key*72;
      short8 ah0 = *(const short8*)(pH + q*8);
      short8 al0 = *(const short8*)(pL + q*8);
      short8 ah1 = *(const short8*)(pH + 32 + q*8);
      short8 al1 = *(const short8*)(pL + 32 + q*8);
      acc[i] = __builtin_amdgcn_mfma_f32_16x16x32_bf16(ah0, bh0, acc[i], 0,0,0);
      acc[i] = __builtin_amdgcn_mfma_f32_16x16x32_bf16(al0, bh0, acc[i], 0,0,0);
      acc[i] = __builtin_amdgcn_mfma_f32_16x16x32_bf16(ah0, bl0, acc[i], 0,0,0);
      acc[i] = __builtin_amdgcn_mfma_f32_16x16x32_bf16(ah1, bh1, acc[i], 0,0,0);
      acc[i] = __builtin_amdgcn_mfma_f32_16x16x32_bf16(al1, bh1, acc[i], 0,0,0);
      acc[i] = __builtin_amdgcn_mfma_f32_16x16x32_bf16(ah1, bl1, acc[i], 0,0,0);
    }
  }
  float bias = convB[L*64 + chl];
  #pragma unroll
  for (int i=0;i<NT;++i){
    #pragma unroll
    for (int reg=0;reg<4;++reg){
      int ni = i*16 + q*4 + reg;
      if (ni < Np){
        float v = acc[i][reg] + bias;
        h[(size_t)(OFFS[L] + ni)*64 + chl] = v > 0.f ? v : 0.f;
      }
    }
  }
  __syncthreads();   // h writes visible + Pt reads done before next level restages
}

__global__ __launch_bounds__(256) void k_tail(float* __restrict__ h,
    const unsigned short* __restrict__ WH, const unsigned short* __restrict__ WLo,
    const float* __restrict__ convB){
  __shared__ unsigned short PtH[257*72];
  __shared__ unsigned short PtL[257*72];
  int t = threadIdx.x;
  tail_level<4>(h, WH + (size_t)3*36864, WLo + (size_t)3*36864, convB, PtH, PtL, t);
  tail_level<3>(h, WH + (size_t)2*36864, WLo + (size_t)2*36864, convB, PtH, PtL, t);
  tail_level<2>(h, WH + (size_t)1*36864, WLo + (size_t)1*36864, convB, PtH, PtL, t);
  tail_level<1>(h, WH,                   WLo,                   convB, PtH, PtL, t);
  // final L=0: h[0] += mean(children h[1..4])
  if (t < 16){
    const float4* c = (const float4*)(h + (size_t)OFFS[1]*64) + t;
    float4 c0 = c[0], c1 = c[16], c2 = c[32], c3 = c[48];
    float4 pr = ((const float4*)h)[t];
    float4 r;
    r.x = 0.25f*(c0.x+c1.x+c2.x+c3.x) + pr.x;
    r.y = 0.25f*(c0.y+c1.y+c2.y+c3.y) + pr.y;
    r.z = 0.25f*(c0.z+c1.z+c2.z+c3.z) + pr.z;
    r.w = 0.25f*(c0.w+c1.w+c2.w+c3.w) + pr.w;
    ((float4*)h)[t] = r;
  }
}

// ---------- emb + LN (MFMA; wave = M-tile, cb looped in-register; zero LDS) ----------
__global__ __launch_bounds__(256) void k_emb(float* __restrict__ h,
    const unsigned short* __restrict__ EH, const unsigned short* __restrict__ ELo,
    const float* __restrict__ embB, const float* __restrict__ lng,
    const float* __restrict__ lnb, const float* __restrict__ gain){
  int bb = blockIdx.x;
  int d = 0;
  #pragma unroll
  for (int i=1;i<=9;++i) if (bb >= EB64[i]) d = i;
  int nb = (bb - EB64[d]) * 64;
  int N = 1 << (2*d);
  int off = OFFS[d];
  int t = threadIdx.x;
  int wt = __builtin_amdgcn_readfirstlane(t >> 6);   // wave = M-tile (16 nodes)
  int lane = t & 63;
  int q = lane >> 4, li = lane & 15;

  // A fragments: this wave's 16 rows, loaded+split ONCE
  const float* rp = h + ((size_t)off + nb + wt*16 + li)*64 + q*8;
  float4 a0 = *(const float4*)rp;
  float4 a1 = *(const float4*)(rp + 4);
  float4 a2 = *(const float4*)(rp + 32);
  float4 a3 = *(const float4*)(rp + 36);
  short8 ah0, al0, ah1, al1;
  split8(a0, a1, ah0, al0);
  split8(a2, a3, ah1, al1);

  f32x4 acc0 = {0.f,0.f,0.f,0.f}, acc1 = acc0, acc2 = acc0, acc3 = acc0;
  #define EMB_CB(CB, ACC) { \
    size_t f0 = (((size_t)(d*2+0)*4 + (CB))*64 + lane)*8; \
    size_t f1 = (((size_t)(d*2+1)*4 + (CB))*64 + lane)*8; \
    short8 bh0 = *(const short8*)(EH + f0); \
    short8 bl0 = *(const short8*)(ELo + f0); \
    short8 bh1 = *(const short8*)(EH + f1); \
    short8 bl1 = *(const short8*)(ELo + f1); \
    ACC = __builtin_amdgcn_mfma_f32_16x16x32_bf16(ah0, bh0, ACC, 0,0,0); \
    ACC = __builtin_amdgcn_mfma_f32_16x16x32_bf16(al0, bh0, ACC, 0,0,0); \
    ACC = __builtin_amdgcn_mfma_f32_16x16x32_bf16(ah0, bl0, ACC, 0,0,0); \
    ACC = __builtin_amdgcn_mfma_f32_16x16x32_bf16(ah1, bh1, ACC, 0,0,0); \
    ACC = __builtin_amdgcn_mfma_f32_16x16x32_bf16(al1, bh1, ACC, 0,0,0); \
    ACC = __builtin_amdgcn_mfma_f32_16x16x32_bf16(ah1, bl1, ACC, 0,0,0); }
  EMB_CB(0, acc0)
  EMB_CB(1, acc1)
  EMB_CB(2, acc2)
  EMB_CB(3, acc3)
  #undef EMB_CB

  float b0 = embB[d*64 +      li];
  float b1 = embB[d*64 + 16 + li];
  float b2 = embB[d*64 + 32 + li];
  float b3 = embB[d*64 + 48 + li];
  float mu[4], rs[4];
  float z0[4], z1[4], z2[4], z3[4];
  #pragma unroll
  for (int r=0;r<4;++r){
    z0[r] = acc0[r] + b0;
    z1[r] = acc1[r] + b1;
    z2[r] = acc2[r] + b2;
    z3[r] = acc3[r] + b3;
    float s  = z0[r] + z1[r] + z2[r] + z3[r];
    float qv = z0[r]*z0[r] + z1[r]*z1[r] + z2[r]*z2[r] + z3[r]*z3[r];
    #pragma unroll
    for (int mk=1; mk<16; mk<<=1){
      s  += __shfl_xor(s, mk, 64);
      qv += __shfl_xor(qv, mk, 64);
    }
    float m = s * 0.015625f;
    mu[r] = m;
    rs[r] = rsqrtf(qv * 0.015625f - m*m + 1e-5f);
  }
  float g0 = lng[d*64 +      li], l0 = lnb[d*64 +      li];
  float g1 = lng[d*64 + 16 + li], l1 = lnb[d*64 + 16 + li];
  float g2 = lng[d*64 + 32 + li], l2 = lnb[d*64 + 32 + li];
  float g3 = lng[d*64 + 48 + li], l3 = lnb[d*64 + 48 + li];
  float gn = gain[d];
  #pragma unroll
  for (int r=0;r<4;++r){
    int ni = wt*16 + q*4 + r;
    if (nb + ni < N){
      float* row = h + ((size_t)off + nb + ni)*64;
      row[     li] = ((z0[r] - mu[r])*rs[r]*g0 + l0)*gn;
      row[16 + li] = ((z1[r] - mu[r])*rs[r]*g1 + l1)*gn;
      row[32 + li] = ((z2[r] - mu[r])*rs[r]*g2 + l2)*gn;
      row[48 + li] = ((z3[r] - mu[r])*rs[r]*g3 + l3)*gn;
    }
  }
}

extern "C" void kernel_launch(void* const* d_in, const int* in_sizes, int n_in,
                              void* d_out, int out_size, void* d_ws, size_t ws_size,
                              hipStream_t stream) {
  (void)in_sizes; (void)n_in; (void)out_size;
  const float* feat  = (const float*)d_in[0];
  const float* ipW   = (const float*)d_in[1];
  const float* ipB   = (const float*)d_in[2];
  const float* convW = (const float*)d_in[3];
  const float* convB = (const float*)d_in[4];
  const float* embW  = (const float*)d_in[5];
  const float* embB  = (const float*)d_in[6];
  const float* lng   = (const float*)d_in[7];
  const float* lnb   = (const float*)d_in[8];
  const float* gain  = (const float*)d_in[9];
  float* h = (float*)d_out;

  unsigned short* WH  = (unsigned short*)d_ws;
  unsigned short* WLo = WH + FRAG_USH;
  float* hpre = (ws_size >= FRAG_BYTES + HPRE_BYTES)
              ? (float*)((char*)d_ws + FRAG_BYTES) : nullptr;

  k_wprep<<<164, 256, 0, stream>>>(convW, embW, WH, WLo);
  k_inproj<<<(TOTAL + 127)/128, 256, 0, stream>>>(feat, ipW, ipB, h, hpre);

  // levels L=8..5 on the grid; L=4..1 inside k_tail
  for (int L = 8; L >= 5; --L){
    int Np = 1 << (2*L);
    const float* hPar = hpre ? (hpre + (size_t)(OFFS[L] - OFFS[4])*64)
                             : (h + (size_t)OFFS[L]*64);
    k_conv<<<Np/64, 256, 0, stream>>>(h, hPar,
        WH  + (size_t)(L-1)*36864, WLo + (size_t)(L-1)*36864,
        convB + (size_t)L*64, Np, OFFS[L], OFFS[L+1], L);
  }

  k_tail<<<1, 256, 0, stream>>>(h, WH, WLo, convB);
  k_emb<<<5464, 256, 0, stream>>>(h, WH + CONV_USH, WLo + CONV_USH,
                                  embB, lng, lnb, gain);
}

// Round 12
// 219.346 us; speedup vs baseline: 2.6119x; 1.0117x over previous
//
#include <hip/hip_runtime.h>
#include <hip/hip_bf16.h>

static constexpr int TOTAL = 349525;
static constexpr int OFFS[11] = {0,1,5,21,85,341,1365,5461,21845,87381,349525};
// emb blocks of 64 nodes per level: counts {1,1,1,1,4,16,64,256,1024,4096}
static constexpr int EB64[11] = {0,1,2,3,4,8,24,88,344,1368,5464};
// conv frags: 8 levels (L=1..8) x 9m x 2ks x 4cb x 64 lanes x 8 bf16
static constexpr size_t CONV_USH = (size_t)8*9*2*4*64*8;    // 294912 ushorts
static constexpr size_t EMB_USH  = (size_t)10*2*4*64*8;     //  40960 ushorts
static constexpr size_t FRAG_USH = CONV_USH + EMB_USH;      // 335872
static constexpr size_t FRAG_BYTES = FRAG_USH*2*2;          // hi+lo = 1343488 B
static constexpr size_t HPRE_BYTES = (size_t)(87381-85)*64*4;

typedef __attribute__((ext_vector_type(8))) short short8;
typedef __attribute__((ext_vector_type(4))) float f32x4;

__device__ __forceinline__ unsigned deint(unsigned v){
  v &= 0x55555555u;
  v = (v | (v>>1)) & 0x33333333u;
  v = (v | (v>>2)) & 0x0F0F0F0Fu;
  v = (v | (v>>4)) & 0x00FF00FFu;
  v = (v | (v>>8)) & 0x0000FFFFu;
  return v;
}
__device__ __forceinline__ unsigned ileave(unsigned v){
  v &= 0xFFFFu;
  v = (v | (v<<8)) & 0x00FF00FFu;
  v = (v | (v<<4)) & 0x0F0F0F0Fu;
  v = (v | (v<<2)) & 0x33333333u;
  v = (v | (v<<1)) & 0x55555555u;
  return v;
}
__device__ __forceinline__ unsigned short f2bh(float x){
  unsigned u = __float_as_uint(x);
  return (unsigned short)((u + 0x7FFFu + ((u>>16)&1u)) >> 16);
}
__device__ __forceinline__ float bh2f(unsigned short h){
  return __uint_as_float(((unsigned)h) << 16);
}
__device__ __forceinline__ void split8(float4 a, float4 b, short8 &hi, short8 &lo){
  float v[8] = {a.x,a.y,a.z,a.w,b.x,b.y,b.z,b.w};
  unsigned short hv[8], lv[8];
  #pragma unroll
  for (int j=0;j<8;++j){ hv[j]=f2bh(v[j]); lv[j]=f2bh(v[j]-bh2f(hv[j])); }
  hi = short8{(short)hv[0],(short)hv[1],(short)hv[2],(short)hv[3],
              (short)hv[4],(short)hv[5],(short)hv[6],(short)hv[7]};
  lo = short8{(short)lv[0],(short)lv[1],(short)lv[2],(short)lv[3],
              (short)lv[4],(short)lv[5],(short)lv[6],(short)lv[7]};
}

// ---------- W prep: conv_W[L=1..8] + emb_W[d=0..9] -> fragment-ordered bf16 hi/lo ----------
__global__ __launch_bounds__(256) void k_wprep(const float* __restrict__ convW,
    const float* __restrict__ embW,
    unsigned short* __restrict__ WH, unsigned short* __restrict__ WLo){
  int tid = blockIdx.x*256 + threadIdx.x;
  if (tid >= 41984) return;
  const float* src;
  size_t dst;
  if (tid < 36864){                       // conv region
    int l=tid&63, cb=(tid>>6)&3, ks=(tid>>8)&1;
    int x=tid>>9; int m=x%9, Lp=x/9;      // L = Lp+1
    int k0=ks*32+((l>>4)<<3), ch=cb*16+(l&15);
    src = convW + (size_t)(Lp+1)*36864 + (size_t)(m*64+k0)*64 + ch;
    dst = (size_t)tid*8;
  } else {                                // emb region
    int t2 = tid - 36864;
    int l=t2&63, cb=(t2>>6)&3, ks=(t2>>8)&1, d=t2>>9;
    int k0=ks*32+((l>>4)<<3), ch=cb*16+(l&15);
    src = embW + (size_t)d*4096 + (size_t)k0*64 + ch;
    dst = CONV_USH + (size_t)t2*8;
  }
  unsigned short hv[8], lv[8];
  #pragma unroll
  for (int j=0;j<8;++j){
    float v = src[(size_t)j*64];
    unsigned short h = f2bh(v);
    hv[j] = h;
    lv[j] = f2bh(v - bh2f(h));
  }
  short8 vh = {(short)hv[0],(short)hv[1],(short)hv[2],(short)hv[3],
               (short)hv[4],(short)hv[5],(short)hv[6],(short)hv[7]};
  short8 vl = {(short)lv[0],(short)lv[1],(short)lv[2],(short)lv[3],
               (short)lv[4],(short)lv[5],(short)lv[6],(short)lv[7]};
  *(short8*)(WH  + dst) = vh;
  *(short8*)(WLo + dst) = vl;
}

// ---------- in_proj (round-7 form + hpre mirror) ----------
__global__ __launch_bounds__(256) void k_inproj(const float* __restrict__ feat,
    const float* __restrict__ W, const float* __restrict__ B,
    float* __restrict__ h, float* __restrict__ hpre){
  __shared__ float Alt[128][44];
  __shared__ float Wl[40][68];
  int t = threadIdx.x;
  int base = blockIdx.x * 128;
  for (int idx = t; idx < 40*64; idx += 256)
    Wl[idx >> 6][idx & 63] = W[idx];
  if (t < 128){
    int g = base + t;
    float* row = Alt[t];
    if (g < TOTAL){
      int d = 0;
      #pragma unroll
      for (int i = 1; i <= 9; ++i) if (g >= OFFS[i]) d = i;
      int local = g - OFFS[d];
      unsigned ix = deint((unsigned)local), iy = deint(((unsigned)local) >> 1);
      float inv = 1.0f / (float)(1 << d);
      float px = ((float)ix + 0.5f) * inv;
      float py = ((float)iy + 0.5f) * inv;
      float pd = (float)d * (1.0f/9.0f);
      row[0] = feat[g]; row[1] = px; row[2] = py; row[3] = pd;
      float p3[3] = {px, py, pd};
      #pragma unroll
      for (int c = 0; c < 3; ++c){
        float s, co;
        __sincosf(6.28318530717958647692f * p3[c], &s, &co);
        float* rb = row + 4 + c*12;
        #pragma unroll
        for (int f = 0; f < 6; ++f){
          rb[f] = s; rb[6+f] = co;
          float s2 = 2.f*s*co, c2 = 1.f - 2.f*s*s;
          s = s2; co = c2;
        }
      }
    } else {
      #pragma unroll
      for (int k = 0; k < 40; ++k) row[k] = 0.f;
    }
  }
  __syncthreads();
  int tr = t >> 3, tc = t & 7;
  float acc[4][8];
  #pragma unroll
  for (int i=0;i<4;++i)
    #pragma unroll
    for (int c=0;c<8;++c) acc[i][c] = 0.f;
  #pragma unroll 2
  for (int k4 = 0; k4 < 10; ++k4){
    float av4[4][4];
    #pragma unroll
    for (int i=0;i<4;++i){
      float4 aa = *(const float4*)&Alt[tr*4+i][k4*4];
      av4[i][0]=aa.x; av4[i][1]=aa.y; av4[i][2]=aa.z; av4[i][3]=aa.w;
    }
    #pragma unroll
    for (int j=0;j<4;++j){
      float4 lo = *(const float4*)&Wl[k4*4+j][tc*8];
      float4 hi = *(const float4*)&Wl[k4*4+j][tc*8+4];
      float wv[8];
      wv[0]=lo.x; wv[1]=lo.y; wv[2]=lo.z; wv[3]=lo.w;
      wv[4]=hi.x; wv[5]=hi.y; wv[6]=hi.z; wv[7]=hi.w;
      #pragma unroll
      for (int i=0;i<4;++i){
        float a = av4[i][j];
        #pragma unroll
        for (int c=0;c<8;++c) acc[i][c] += a*wv[c];
      }
    }
  }
  #pragma unroll
  for (int i=0;i<4;++i){
    int g = base + tr*4 + i;
    if (g >= TOTAL) continue;
    float ov[8];
    #pragma unroll
    for (int c=0;c<8;++c) ov[c] = acc[i][c] + B[tc*8+c];
    float* dst = &h[(size_t)g*64 + tc*8];
    *(float4*)dst       = *(const float4*)&ov[0];
    *(float4*)(dst + 4) = *(const float4*)&ov[4];
    if (hpre && g >= OFFS[4] && g < OFFS[9]){
      float* dp = hpre + (size_t)(g - OFFS[4])*64 + tc*8;
      *(float4*)dp       = *(const float4*)&ov[0];
      *(float4*)(dp + 4) = *(const float4*)&ov[4];
    }
  }
}

// ---------- conv (halo + fused pool + MFMA bf16-split) — verified ----------
__global__ __launch_bounds__(256) void k_conv(float* __restrict__ h,
    const float* __restrict__ hPar,
    const unsigned short* __restrict__ WHl, const unsigned short* __restrict__ WLl,
    const float* __restrict__ Bb, int N, int offL, int offC, int lbits){
  __shared__ unsigned short haloH[100*72];
  __shared__ unsigned short haloL[100*72];
  __shared__ int hkey[100];
  int t = threadIdx.x;
  int nb = blockIdx.x * 64;
  int res = 1 << lbits;
  if (t < 100){
    int i = t % 10, j = t / 10;
    int gx = (int)deint((unsigned)nb) - 1 + i;
    int gy = (int)deint(((unsigned)nb)>>1) - 1 + j;
    bool ok = (gx>=0 && gy>=0 && gx<res && gy<res);
    hkey[t] = ok ? (int)(ileave((unsigned)gx) | (ileave((unsigned)gy)<<1)) : -1;
  }
  __syncthreads();
  const float* hC = h + (size_t)offC*64;
  for (int e = t; e < 1600; e += 256){
    int hi_ = e >> 4, u = e & 15;
    int key = hkey[hi_];
    float4 r = make_float4(0.f,0.f,0.f,0.f);
    if (key >= 0){
      const float4* c = (const float4*)(hC + (size_t)(4*key)*64) + u;
      float4 c0 = c[0], c1 = c[16], c2 = c[32], c3 = c[48];
      float4 pr = *((const float4*)(hPar + (size_t)key*64) + u);
      r.x = 0.25f*(c0.x+c1.x+c2.x+c3.x) + pr.x;
      r.y = 0.25f*(c0.y+c1.y+c2.y+c3.y) + pr.y;
      r.z = 0.25f*(c0.z+c1.z+c2.z+c3.z) + pr.z;
      r.w = 0.25f*(c0.w+c1.w+c2.w+c3.w) + pr.w;
    }
    unsigned short h0=f2bh(r.x), h1=f2bh(r.y), h2=f2bh(r.z), h3=f2bh(r.w);
    ushort4 rh = make_ushort4(h0,h1,h2,h3);
    ushort4 rl = make_ushort4(f2bh(r.x - bh2f(h0)), f2bh(r.y - bh2f(h1)),
                              f2bh(r.z - bh2f(h2)), f2bh(r.w - bh2f(h3)));
    *(ushort4*)&haloH[hi_*72 + u*4] = rh;
    *(ushort4*)&haloL[hi_*72 + u*4] = rl;
  }
  __syncthreads();

  int cb   = __builtin_amdgcn_readfirstlane((int)(threadIdx.x >> 6));
  int lane = t & 63;
  int q = lane >> 4;
  int chl = cb*16 + (lane & 15);
  int lx0,ly0,lx1,ly1,lx2,ly2,lx3,ly3;
  {
    int n0 = (lane&15), n1 = 16+(lane&15), n2 = 32+(lane&15), n3 = 48+(lane&15);
    lx0=(int)deint((unsigned)n0); ly0=(int)deint(((unsigned)n0)>>1);
    lx1=(int)deint((unsigned)n1); ly1=(int)deint(((unsigned)n1)>>1);
    lx2=(int)deint((unsigned)n2); ly2=(int)deint(((unsigned)n2)>>1);
    lx3=(int)deint((unsigned)n3); ly3=(int)deint(((unsigned)n3)>>1);
  }
  f32x4 acc0 = {0.f,0.f,0.f,0.f}, acc1 = acc0, acc2 = acc0, acc3 = acc0;

  #pragma unroll 1
  for (int dy=0;dy<3;++dy){
    #pragma unroll 1
    for (int dx=0;dx<3;++dx){
      int m = dy*3 + dx;
      int r0 = (ly0+dy)*10 + lx0+dx;
      int r1 = (ly1+dy)*10 + lx1+dx;
      int r2 = (ly2+dy)*10 + lx2+dx;
      int r3 = (ly3+dy)*10 + lx3+dx;
      #pragma unroll
      for (int ks=0;ks<2;++ks){
        const unsigned short* fp = WHl + ((size_t)((m*2+ks)*4 + cb)*64 + lane)*8;
        const unsigned short* fq = WLl + ((size_t)((m*2+ks)*4 + cb)*64 + lane)*8;
        short8 bh = *(const short8*)fp;
        short8 bl = *(const short8*)fq;
        int so = (ks*4 + q)*8;
        short8 ah0 = *(const short8*)&haloH[r0*72 + so];
        short8 al0 = *(const short8*)&haloL[r0*72 + so];
        short8 ah1 = *(const short8*)&haloH[r1*72 + so];
        short8 al1 = *(const short8*)&haloL[r1*72 + so];
        short8 ah2 = *(const short8*)&haloH[r2*72 + so];
        short8 al2 = *(const short8*)&haloL[r2*72 + so];
        short8 ah3 = *(const short8*)&haloH[r3*72 + so];
        short8 al3 = *(const short8*)&haloL[r3*72 + so];
        acc0 = __builtin_amdgcn_mfma_f32_16x16x32_bf16(ah0, bh, acc0, 0,0,0);
        acc1 = __builtin_amdgcn_mfma_f32_16x16x32_bf16(ah1, bh, acc1, 0,0,0);
        acc2 = __builtin_amdgcn_mfma_f32_16x16x32_bf16(ah2, bh, acc2, 0,0,0);
        acc3 = __builtin_amdgcn_mfma_f32_16x16x32_bf16(ah3, bh, acc3, 0,0,0);
        acc0 = __builtin_amdgcn_mfma_f32_16x16x32_bf16(al0, bh, acc0, 0,0,0);
        acc1 = __builtin_amdgcn_mfma_f32_16x16x32_bf16(al1, bh, acc1, 0,0,0);
        acc2 = __builtin_amdgcn_mfma_f32_16x16x32_bf16(al2, bh, acc2, 0,0,0);
        acc3 = __builtin_amdgcn_mfma_f32_16x16x32_bf16(al3, bh, acc3, 0,0,0);
        acc0 = __builtin_amdgcn_mfma_f32_16x16x32_bf16(ah0, bl, acc0, 0,0,0);
        acc1 = __builtin_amdgcn_mfma_f32_16x16x32_bf16(ah1, bl, acc1, 0,0,0);
        acc2 = __builtin_amdgcn_mfma_f32_16x16x32_bf16(ah2, bl, acc2, 0,0,0);
        acc3 = __builtin_amdgcn_mfma_f32_16x16x32_bf16(ah3, bl, acc3, 0,0,0);
      }
    }
  }
  float bias = Bb[chl];
  int rowb = q*4;
  float* hO = h + (size_t)(offL + nb)*64;
  #pragma unroll
  for (int reg=0;reg<4;++reg){
    int n0 = rowb + reg;
    float v0 = acc0[reg] + bias; if (nb + n0      < N) hO[(size_t)(n0     )*64 + chl] = v0 > 0.f ? v0 : 0.f;
    float v1 = acc1[reg] + bias; if (nb + n0 + 16 < N) hO[(size_t)(n0 + 16)*64 + chl] = v1 > 0.f ? v1 : 0.f;
    float v2 = acc2[reg] + bias; if (nb + n0 + 32 < N) hO[(size_t)(n0 + 32)*64 + chl] = v2 > 0.f ? v2 : 0.f;
    float v3 = acc3[reg] + bias; if (nb + n0 + 48 < N) hO[(size_t)(n0 + 48)*64 + chl] = v3 > 0.f ? v3 : 0.f;
  }
}

// ---------- tail level L (MFMA, 1024 threads): wave = (cb, tile-group) ----------
template<int L>
__device__ __forceinline__ void tail_level(float* __restrict__ h,
    const unsigned short* __restrict__ WHc, const unsigned short* __restrict__ WLc,
    const float* __restrict__ convB,
    unsigned short* __restrict__ PtH, unsigned short* __restrict__ PtL, int t){
  constexpr int Np  = 1 << (2*L);
  constexpr int NTt = (Np + 15)/16;     // total M-tiles: 16,4,1,1
  constexpr int TG  = (NTt + 3)/4;      // tiles per wave: 4,1,1,1
  constexpr int res = 1 << L;
  // stage pooled rows; row Np = zero row for invalid neighbors
  for (int e = t; e < (Np+1)*16; e += 1024){
    int node = e >> 4, u = e & 15;
    float4 r = make_float4(0.f,0.f,0.f,0.f);
    if (node < Np){
      const float4* c = (const float4*)(h + (size_t)(OFFS[L+1] + 4*node)*64) + u;
      float4 c0 = c[0], c1 = c[16], c2 = c[32], c3 = c[48];
      float4 pr = *((const float4*)(h + (size_t)(OFFS[L] + node)*64) + u);
      r.x = 0.25f*(c0.x+c1.x+c2.x+c3.x) + pr.x;
      r.y = 0.25f*(c0.y+c1.y+c2.y+c3.y) + pr.y;
      r.z = 0.25f*(c0.z+c1.z+c2.z+c3.z) + pr.z;
      r.w = 0.25f*(c0.w+c1.w+c2.w+c3.w) + pr.w;
    }
    unsigned short h0=f2bh(r.x), h1=f2bh(r.y), h2=f2bh(r.z), h3=f2bh(r.w);
    *(ushort4*)&PtH[node*72 + u*4] = make_ushort4(h0,h1,h2,h3);
    *(ushort4*)&PtL[node*72 + u*4] = make_ushort4(
        f2bh(r.x - bh2f(h0)), f2bh(r.y - bh2f(h1)),
        f2bh(r.z - bh2f(h2)), f2bh(r.w - bh2f(h3)));
  }
  __syncthreads();
  int w  = t >> 6;
  int cb = __builtin_amdgcn_readfirstlane(w & 3);
  int tg = __builtin_amdgcn_readfirstlane(w >> 2);
  int lane = t & 63;
  int q = lane >> 4;
  int chl = cb*16 + (lane & 15);
  int lx[TG], ly[TG];
  #pragma unroll
  for (int i=0;i<TG;++i){
    unsigned n = (unsigned)((tg*TG + i)*16 + (lane & 15));
    lx[i] = (int)deint(n); ly[i] = (int)deint(n >> 1);
  }
  f32x4 acc[TG];
  #pragma unroll
  for (int i=0;i<TG;++i) acc[i] = f32x4{0.f,0.f,0.f,0.f};
  #pragma unroll 1
  for (int m=0;m<9;++m){
    int dy = m/3 - 1, dx = m%3 - 1;
    size_t f0 = ((size_t)((m*2+0)*4 + cb)*64 + lane)*8;
    size_t f1 = ((size_t)((m*2+1)*4 + cb)*64 + lane)*8;
    short8 bh0 = *(const short8*)(WHc + f0);
    short8 bl0 = *(const short8*)(WLc + f0);
    short8 bh1 = *(const short8*)(WHc + f1);
    short8 bl1 = *(const short8*)(WLc + f1);
    #pragma unroll
    for (int i=0;i<TG;++i){
      int nx = lx[i]+dx, ny = ly[i]+dy;
      int key = (nx>=0 && ny>=0 && nx<res && ny<res)
              ? (int)(ileave((unsigned)nx) | (ileave((unsigned)ny)<<1)) : Np;
      const unsigned short* pH = PtH + key*72;
      const unsigned short* pL = PtL + key*72;
      short8 ah0 = *(const short8*)(pH + q*8);
      short8 al0 = *(const short8*)(pL + q*8);
      short8 ah1 = *(const short8*)(pH + 32 + q*8);
      short8 al1 = *(const short8*)(pL + 32 + q*8);
      acc[i] = __builtin_amdgcn_mfma_f32_16x16x32_bf16(ah0, bh0, acc[i], 0,0,0);
      acc[i] = __builtin_amdgcn_mfma_f32_16x16x32_bf16(al0, bh0, acc[i], 0,0,0);
      acc[i] = __builtin_amdgcn_mfma_f32_16x16x32_bf16(ah0, bl0, acc[i], 0,0,0);
      acc[i] = __builtin_amdgcn_mfma_f32_16x16x32_bf16(ah1, bh1, acc[i], 0,0,0);
      acc[i] = __builtin_amdgcn_mfma_f32_16x16x32_bf16(al1, bh1, acc[i], 0,0,0);
      acc[i] = __builtin_amdgcn_mfma_f32_16x16x32_bf16(ah1, bl1, acc[i], 0,0,0);
    }
  }
  float bias = convB[L*64 + chl];
  #pragma unroll
  for (int i=0;i<TG;++i){
    #pragma unroll
    for (int reg=0;reg<4;++reg){
      int ni = (tg*TG + i)*16 + q*4 + reg;
      if (ni < Np){
        float v = acc[i][reg] + bias;
        h[(size_t)(OFFS[L] + ni)*64 + chl] = v > 0.f ? v : 0.f;
      }
    }
  }
  __syncthreads();   // h writes visible + Pt reads done before next level restages
}

__global__ __launch_bounds__(1024) void k_tail(float* __restrict__ h,
    const unsigned short* __restrict__ WH, const unsigned short* __restrict__ WLo,
    const float* __restrict__ convB){
  __shared__ unsigned short PtH[257*72];
  __shared__ unsigned short PtL[257*72];
  int t = threadIdx.x;
  tail_level<4>(h, WH + (size_t)3*36864, WLo + (size_t)3*36864, convB, PtH, PtL, t);
  tail_level<3>(h, WH + (size_t)2*36864, WLo + (size_t)2*36864, convB, PtH, PtL, t);
  tail_level<2>(h, WH + (size_t)1*36864, WLo + (size_t)1*36864, convB, PtH, PtL, t);
  tail_level<1>(h, WH,                   WLo,                   convB, PtH, PtL, t);
  // final L=0: h[0] += mean(children h[1..4])
  if (t < 16){
    const float4* c = (const float4*)(h + (size_t)OFFS[1]*64) + t;
    float4 c0 = c[0], c1 = c[16], c2 = c[32], c3 = c[48];
    float4 pr = ((const float4*)h)[t];
    float4 r;
    r.x = 0.25f*(c0.x+c1.x+c2.x+c3.x) + pr.x;
    r.y = 0.25f*(c0.y+c1.y+c2.y+c3.y) + pr.y;
    r.z = 0.25f*(c0.z+c1.z+c2.z+c3.z) + pr.z;
    r.w = 0.25f*(c0.w+c1.w+c2.w+c3.w) + pr.w;
    ((float4*)h)[t] = r;
  }
}

// ---------- emb + LN (MFMA; wave = M-tile, cb looped in-register; zero LDS) ----------
__global__ __launch_bounds__(256) void k_emb(float* __restrict__ h,
    const unsigned short* __restrict__ EH, const unsigned short* __restrict__ ELo,
    const float* __restrict__ embB, const float* __restrict__ lng,
    const float* __restrict__ lnb, const float* __restrict__ gain){
  int bb = blockIdx.x;
  int d = 0;
  #pragma unroll
  for (int i=1;i<=9;++i) if (bb >= EB64[i]) d = i;
  int nb = (bb - EB64[d]) * 64;
  int N = 1 << (2*d);
  int off = OFFS[d];
  int t = threadIdx.x;
  int wt = __builtin_amdgcn_readfirstlane(t >> 6);   // wave = M-tile (16 nodes)
  int lane = t & 63;
  int q = lane >> 4, li = lane & 15;

  // A fragments: this wave's 16 rows, loaded+split ONCE
  const float* rp = h + ((size_t)off + nb + wt*16 + li)*64 + q*8;
  float4 a0 = *(const float4*)rp;
  float4 a1 = *(const float4*)(rp + 4);
  float4 a2 = *(const float4*)(rp + 32);
  float4 a3 = *(const float4*)(rp + 36);
  short8 ah0, al0, ah1, al1;
  split8(a0, a1, ah0, al0);
  split8(a2, a3, ah1, al1);

  f32x4 acc0 = {0.f,0.f,0.f,0.f}, acc1 = acc0, acc2 = acc0, acc3 = acc0;
  #define EMB_CB(CB, ACC) { \
    size_t f0 = (((size_t)(d*2+0)*4 + (CB))*64 + lane)*8; \
    size_t f1 = (((size_t)(d*2+1)*4 + (CB))*64 + lane)*8; \
    short8 bh0 = *(const short8*)(EH + f0); \
    short8 bl0 = *(const short8*)(ELo + f0); \
    short8 bh1 = *(const short8*)(EH + f1); \
    short8 bl1 = *(const short8*)(ELo + f1); \
    ACC = __builtin_amdgcn_mfma_f32_16x16x32_bf16(ah0, bh0, ACC, 0,0,0); \
    ACC = __builtin_amdgcn_mfma_f32_16x16x32_bf16(al0, bh0, ACC, 0,0,0); \
    ACC = __builtin_amdgcn_mfma_f32_16x16x32_bf16(ah0, bl0, ACC, 0,0,0); \
    ACC = __builtin_amdgcn_mfma_f32_16x16x32_bf16(ah1, bh1, ACC, 0,0,0); \
    ACC = __builtin_amdgcn_mfma_f32_16x16x32_bf16(al1, bh1, ACC, 0,0,0); \
    ACC = __builtin_amdgcn_mfma_f32_16x16x32_bf16(ah1, bl1, ACC, 0,0,0); }
  EMB_CB(0, acc0)
  EMB_CB(1, acc1)
  EMB_CB(2, acc2)
  EMB_CB(3, acc3)
  #undef EMB_CB

  float b0 = embB[d*64 +      li];
  float b1 = embB[d*64 + 16 + li];
  float b2 = embB[d*64 + 32 + li];
  float b3 = embB[d*64 + 48 + li];
  float mu[4], rs[4];
  float z0[4], z1[4], z2[4], z3[4];
  #pragma unroll
  for (int r=0;r<4;++r){
    z0[r] = acc0[r] + b0;
    z1[r] = acc1[r] + b1;
    z2[r] = acc2[r] + b2;
    z3[r] = acc3[r] + b3;
    float s  = z0[r] + z1[r] + z2[r] + z3[r];
    float qv = z0[r]*z0[r] + z1[r]*z1[r] + z2[r]*z2[r] + z3[r]*z3[r];
    #pragma unroll
    for (int mk=1; mk<16; mk<<=1){
      s  += __shfl_xor(s, mk, 64);
      qv += __shfl_xor(qv, mk, 64);
    }
    float m = s * 0.015625f;
    mu[r] = m;
    rs[r] = rsqrtf(qv * 0.015625f - m*m + 1e-5f);
  }
  float g0 = lng[d*64 +      li], l0 = lnb[d*64 +      li];
  float g1 = lng[d*64 + 16 + li], l1 = lnb[d*64 + 16 + li];
  float g2 = lng[d*64 + 32 + li], l2 = lnb[d*64 + 32 + li];
  float g3 = lng[d*64 + 48 + li], l3 = lnb[d*64 + 48 + li];
  float gn = gain[d];
  #pragma unroll
  for (int r=0;r<4;++r){
    int ni = wt*16 + q*4 + r;
    if (nb + ni < N){
      float* row = h + ((size_t)off + nb + ni)*64;
      row[     li] = ((z0[r] - mu[r])*rs[r]*g0 + l0)*gn;
      row[16 + li] = ((z1[r] - mu[r])*rs[r]*g1 + l1)*gn;
      row[32 + li] = ((z2[r] - mu[r])*rs[r]*g2 + l2)*gn;
      row[48 + li] = ((z3[r] - mu[r])*rs[r]*g3 + l3)*gn;
    }
  }
}

extern "C" void kernel_launch(void* const* d_in, const int* in_sizes, int n_in,
                              void* d_out, int out_size, void* d_ws, size_t ws_size,
                              hipStream_t stream) {
  (void)in_sizes; (void)n_in; (void)out_size;
  const float* feat  = (const float*)d_in[0];
  const float* ipW   = (const float*)d_in[1];
  const float* ipB   = (const float*)d_in[2];
  const float* convW = (const float*)d_in[3];
  const float* convB = (const float*)d_in[4];
  const float* embW  = (const float*)d_in[5];
  const float* embB  = (const float*)d_in[6];
  const float* lng   = (const float*)d_in[7];
  const float* lnb   = (const float*)d_in[8];
  const float* gain  = (const float*)d_in[9];
  float* h = (float*)d_out;

  unsigned short* WH  = (unsigned short*)d_ws;
  unsigned short* WLo = WH + FRAG_USH;
  float* hpre = (ws_size >= FRAG_BYTES + HPRE_BYTES)
              ? (float*)((char*)d_ws + FRAG_BYTES) : nullptr;

  k_wprep<<<164, 256, 0, stream>>>(convW, embW, WH, WLo);
  k_inproj<<<(TOTAL + 127)/128, 256, 0, stream>>>(feat, ipW, ipB, h, hpre);

  // levels L=8..5 on the grid; L=4..1 inside k_tail
  for (int L = 8; L >= 5; --L){
    int Np = 1 << (2*L);
    const float* hPar = hpre ? (hpre + (size_t)(OFFS[L] - OFFS[4])*64)
                             : (h + (size_t)OFFS[L]*64);
    k_conv<<<Np/64, 256, 0, stream>>>(h, hPar,
        WH  + (size_t)(L-1)*36864, WLo + (size_t)(L-1)*36864,
        convB + (size_t)L*64, Np, OFFS[L], OFFS[L+1], L);
  }

  k_tail<<<1, 1024, 0, stream>>>(h, WH, WLo, convB);
  k_emb<<<5464, 256, 0, stream>>>(h, WH + CONV_USH, WLo + CONV_USH,
                                  embB, lng, lnb, gain);
}

// Round 13
// 205.593 us; speedup vs baseline: 2.7866x; 1.0669x over previous
//
#include <hip/hip_runtime.h>
#include <hip/hip_bf16.h>

static constexpr int TOTAL = 349525;
static constexpr int OFFS[11] = {0,1,5,21,85,341,1365,5461,21845,87381,349525};
// emb blocks of 64 nodes per level: counts {1,1,1,1,4,16,64,256,1024,4096}
static constexpr int EB64[11] = {0,1,2,3,4,8,24,88,344,1368,5464};
// conv frags: 8 levels (L=1..8) x 9m x 2ks x 4cb x 64 lanes x 8 bf16
static constexpr size_t CONV_USH = (size_t)8*9*2*4*64*8;    // 294912 ushorts
static constexpr size_t EMB_USH  = (size_t)10*2*4*64*8;     //  40960 ushorts
static constexpr size_t FRAG_USH = CONV_USH + EMB_USH;      // 335872
static constexpr size_t FRAG_BYTES = FRAG_USH*2*2;          // hi+lo = 1343488 B
static constexpr size_t HPRE_BYTES = (size_t)(87381-85)*64*4;

typedef __attribute__((ext_vector_type(8))) short short8;
typedef __attribute__((ext_vector_type(4))) float f32x4;

__device__ __forceinline__ unsigned deint(unsigned v){
  v &= 0x55555555u;
  v = (v | (v>>1)) & 0x33333333u;
  v = (v | (v>>2)) & 0x0F0F0F0Fu;
  v = (v | (v>>4)) & 0x00FF00FFu;
  v = (v | (v>>8)) & 0x0000FFFFu;
  return v;
}
__device__ __forceinline__ unsigned ileave(unsigned v){
  v &= 0xFFFFu;
  v = (v | (v<<8)) & 0x00FF00FFu;
  v = (v | (v<<4)) & 0x0F0F0F0Fu;
  v = (v | (v<<2)) & 0x33333333u;
  v = (v | (v<<1)) & 0x55555555u;
  return v;
}
__device__ __forceinline__ unsigned short f2bh(float x){
  unsigned u = __float_as_uint(x);
  return (unsigned short)((u + 0x7FFFu + ((u>>16)&1u)) >> 16);
}
__device__ __forceinline__ float bh2f(unsigned short h){
  return __uint_as_float(((unsigned)h) << 16);
}
__device__ __forceinline__ void split8(float4 a, float4 b, short8 &hi, short8 &lo){
  float v[8] = {a.x,a.y,a.z,a.w,b.x,b.y,b.z,b.w};
  unsigned short hv[8], lv[8];
  #pragma unroll
  for (int j=0;j<8;++j){ hv[j]=f2bh(v[j]); lv[j]=f2bh(v[j]-bh2f(hv[j])); }
  hi = short8{(short)hv[0],(short)hv[1],(short)hv[2],(short)hv[3],
              (short)hv[4],(short)hv[5],(short)hv[6],(short)hv[7]};
  lo = short8{(short)lv[0],(short)lv[1],(short)lv[2],(short)lv[3],
              (short)lv[4],(short)lv[5],(short)lv[6],(short)lv[7]};
}

// ---------- W prep: conv_W[L=1..8] + emb_W[d=0..9] -> fragment-ordered bf16 hi/lo ----------
__global__ __launch_bounds__(256) void k_wprep(const float* __restrict__ convW,
    const float* __restrict__ embW,
    unsigned short* __restrict__ WH, unsigned short* __restrict__ WLo){
  int tid = blockIdx.x*256 + threadIdx.x;
  if (tid >= 41984) return;
  const float* src;
  size_t dst;
  if (tid < 36864){                       // conv region
    int l=tid&63, cb=(tid>>6)&3, ks=(tid>>8)&1;
    int x=tid>>9; int m=x%9, Lp=x/9;      // L = Lp+1
    int k0=ks*32+((l>>4)<<3), ch=cb*16+(l&15);
    src = convW + (size_t)(Lp+1)*36864 + (size_t)(m*64+k0)*64 + ch;
    dst = (size_t)tid*8;
  } else {                                // emb region
    int t2 = tid - 36864;
    int l=t2&63, cb=(t2>>6)&3, ks=(t2>>8)&1, d=t2>>9;
    int k0=ks*32+((l>>4)<<3), ch=cb*16+(l&15);
    src = embW + (size_t)d*4096 + (size_t)k0*64 + ch;
    dst = CONV_USH + (size_t)t2*8;
  }
  unsigned short hv[8], lv[8];
  #pragma unroll
  for (int j=0;j<8;++j){
    float v = src[(size_t)j*64];
    unsigned short h = f2bh(v);
    hv[j] = h;
    lv[j] = f2bh(v - bh2f(h));
  }
  short8 vh = {(short)hv[0],(short)hv[1],(short)hv[2],(short)hv[3],
               (short)hv[4],(short)hv[5],(short)hv[6],(short)hv[7]};
  short8 vl = {(short)lv[0],(short)lv[1],(short)lv[2],(short)lv[3],
               (short)lv[4],(short)lv[5],(short)lv[6],(short)lv[7]};
  *(short8*)(WH  + dst) = vh;
  *(short8*)(WLo + dst) = vl;
}

// ---------- in_proj (round-7 form + hpre mirror) ----------
__global__ __launch_bounds__(256) void k_inproj(const float* __restrict__ feat,
    const float* __restrict__ W, const float* __restrict__ B,
    float* __restrict__ h, float* __restrict__ hpre){
  __shared__ float Alt[128][44];
  __shared__ float Wl[40][68];
  int t = threadIdx.x;
  int base = blockIdx.x * 128;
  for (int idx = t; idx < 40*64; idx += 256)
    Wl[idx >> 6][idx & 63] = W[idx];
  if (t < 128){
    int g = base + t;
    float* row = Alt[t];
    if (g < TOTAL){
      int d = 0;
      #pragma unroll
      for (int i = 1; i <= 9; ++i) if (g >= OFFS[i]) d = i;
      int local = g - OFFS[d];
      unsigned ix = deint((unsigned)local), iy = deint(((unsigned)local) >> 1);
      float inv = 1.0f / (float)(1 << d);
      float px = ((float)ix + 0.5f) * inv;
      float py = ((float)iy + 0.5f) * inv;
      float pd = (float)d * (1.0f/9.0f);
      row[0] = feat[g]; row[1] = px; row[2] = py; row[3] = pd;
      float p3[3] = {px, py, pd};
      #pragma unroll
      for (int c = 0; c < 3; ++c){
        float s, co;
        __sincosf(6.28318530717958647692f * p3[c], &s, &co);
        float* rb = row + 4 + c*12;
        #pragma unroll
        for (int f = 0; f < 6; ++f){
          rb[f] = s; rb[6+f] = co;
          float s2 = 2.f*s*co, c2 = 1.f - 2.f*s*s;
          s = s2; co = c2;
        }
      }
    } else {
      #pragma unroll
      for (int k = 0; k < 40; ++k) row[k] = 0.f;
    }
  }
  __syncthreads();
  int tr = t >> 3, tc = t & 7;
  float acc[4][8];
  #pragma unroll
  for (int i=0;i<4;++i)
    #pragma unroll
    for (int c=0;c<8;++c) acc[i][c] = 0.f;
  #pragma unroll 2
  for (int k4 = 0; k4 < 10; ++k4){
    float av4[4][4];
    #pragma unroll
    for (int i=0;i<4;++i){
      float4 aa = *(const float4*)&Alt[tr*4+i][k4*4];
      av4[i][0]=aa.x; av4[i][1]=aa.y; av4[i][2]=aa.z; av4[i][3]=aa.w;
    }
    #pragma unroll
    for (int j=0;j<4;++j){
      float4 lo = *(const float4*)&Wl[k4*4+j][tc*8];
      float4 hi = *(const float4*)&Wl[k4*4+j][tc*8+4];
      float wv[8];
      wv[0]=lo.x; wv[1]=lo.y; wv[2]=lo.z; wv[3]=lo.w;
      wv[4]=hi.x; wv[5]=hi.y; wv[6]=hi.z; wv[7]=hi.w;
      #pragma unroll
      for (int i=0;i<4;++i){
        float a = av4[i][j];
        #pragma unroll
        for (int c=0;c<8;++c) acc[i][c] += a*wv[c];
      }
    }
  }
  #pragma unroll
  for (int i=0;i<4;++i){
    int g = base + tr*4 + i;
    if (g >= TOTAL) continue;
    float ov[8];
    #pragma unroll
    for (int c=0;c<8;++c) ov[c] = acc[i][c] + B[tc*8+c];
    float* dst = &h[(size_t)g*64 + tc*8];
    *(float4*)dst       = *(const float4*)&ov[0];
    *(float4*)(dst + 4) = *(const float4*)&ov[4];
    if (hpre && g >= OFFS[4] && g < OFFS[9]){
      float* dp = hpre + (size_t)(g - OFFS[4])*64 + tc*8;
      *(float4*)dp       = *(const float4*)&ov[0];
      *(float4*)(dp + 4) = *(const float4*)&ov[4];
    }
  }
}

// ---------- conv (halo + fused pool + MFMA bf16-split) — verified ----------
__global__ __launch_bounds__(256) void k_conv(float* __restrict__ h,
    const float* __restrict__ hPar,
    const unsigned short* __restrict__ WHl, const unsigned short* __restrict__ WLl,
    const float* __restrict__ Bb, int N, int offL, int offC, int lbits){
  __shared__ unsigned short haloH[100*72];
  __shared__ unsigned short haloL[100*72];
  __shared__ int hkey[100];
  int t = threadIdx.x;
  int nb = blockIdx.x * 64;
  int res = 1 << lbits;
  if (t < 100){
    int i = t % 10, j = t / 10;
    int gx = (int)deint((unsigned)nb) - 1 + i;
    int gy = (int)deint(((unsigned)nb)>>1) - 1 + j;
    bool ok = (gx>=0 && gy>=0 && gx<res && gy<res);
    hkey[t] = ok ? (int)(ileave((unsigned)gx) | (ileave((unsigned)gy)<<1)) : -1;
  }
  __syncthreads();
  const float* hC = h + (size_t)offC*64;
  for (int e = t; e < 1600; e += 256){
    int hi_ = e >> 4, u = e & 15;
    int key = hkey[hi_];
    float4 r = make_float4(0.f,0.f,0.f,0.f);
    if (key >= 0){
      const float4* c = (const float4*)(hC + (size_t)(4*key)*64) + u;
      float4 c0 = c[0], c1 = c[16], c2 = c[32], c3 = c[48];
      float4 pr = *((const float4*)(hPar + (size_t)key*64) + u);
      r.x = 0.25f*(c0.x+c1.x+c2.x+c3.x) + pr.x;
      r.y = 0.25f*(c0.y+c1.y+c2.y+c3.y) + pr.y;
      r.z = 0.25f*(c0.z+c1.z+c2.z+c3.z) + pr.z;
      r.w = 0.25f*(c0.w+c1.w+c2.w+c3.w) + pr.w;
    }
    unsigned short h0=f2bh(r.x), h1=f2bh(r.y), h2=f2bh(r.z), h3=f2bh(r.w);
    ushort4 rh = make_ushort4(h0,h1,h2,h3);
    ushort4 rl = make_ushort4(f2bh(r.x - bh2f(h0)), f2bh(r.y - bh2f(h1)),
                              f2bh(r.z - bh2f(h2)), f2bh(r.w - bh2f(h3)));
    *(ushort4*)&haloH[hi_*72 + u*4] = rh;
    *(ushort4*)&haloL[hi_*72 + u*4] = rl;
  }
  __syncthreads();

  int cb   = __builtin_amdgcn_readfirstlane((int)(threadIdx.x >> 6));
  int lane = t & 63;
  int q = lane >> 4;
  int chl = cb*16 + (lane & 15);
  int lx0,ly0,lx1,ly1,lx2,ly2,lx3,ly3;
  {
    int n0 = (lane&15), n1 = 16+(lane&15), n2 = 32+(lane&15), n3 = 48+(lane&15);
    lx0=(int)deint((unsigned)n0); ly0=(int)deint(((unsigned)n0)>>1);
    lx1=(int)deint((unsigned)n1); ly1=(int)deint(((unsigned)n1)>>1);
    lx2=(int)deint((unsigned)n2); ly2=(int)deint(((unsigned)n2)>>1);
    lx3=(int)deint((unsigned)n3); ly3=(int)deint(((unsigned)n3)>>1);
  }
  f32x4 acc0 = {0.f,0.f,0.f,0.f}, acc1 = acc0, acc2 = acc0, acc3 = acc0;

  #pragma unroll 1
  for (int dy=0;dy<3;++dy){
    #pragma unroll 1
    for (int dx=0;dx<3;++dx){
      int m = dy*3 + dx;
      int r0 = (ly0+dy)*10 + lx0+dx;
      int r1 = (ly1+dy)*10 + lx1+dx;
      int r2 = (ly2+dy)*10 + lx2+dx;
      int r3 = (ly3+dy)*10 + lx3+dx;
      #pragma unroll
      for (int ks=0;ks<2;++ks){
        const unsigned short* fp = WHl + ((size_t)((m*2+ks)*4 + cb)*64 + lane)*8;
        const unsigned short* fq = WLl + ((size_t)((m*2+ks)*4 + cb)*64 + lane)*8;
        short8 bh = *(const short8*)fp;
        short8 bl = *(const short8*)fq;
        int so = (ks*4 + q)*8;
        short8 ah0 = *(const short8*)&haloH[r0*72 + so];
        short8 al0 = *(const short8*)&haloL[r0*72 + so];
        short8 ah1 = *(const short8*)&haloH[r1*72 + so];
        short8 al1 = *(const short8*)&haloL[r1*72 + so];
        short8 ah2 = *(const short8*)&haloH[r2*72 + so];
        short8 al2 = *(const short8*)&haloL[r2*72 + so];
        short8 ah3 = *(const short8*)&haloH[r3*72 + so];
        short8 al3 = *(const short8*)&haloL[r3*72 + so];
        acc0 = __builtin_amdgcn_mfma_f32_16x16x32_bf16(ah0, bh, acc0, 0,0,0);
        acc1 = __builtin_amdgcn_mfma_f32_16x16x32_bf16(ah1, bh, acc1, 0,0,0);
        acc2 = __builtin_amdgcn_mfma_f32_16x16x32_bf16(ah2, bh, acc2, 0,0,0);
        acc3 = __builtin_amdgcn_mfma_f32_16x16x32_bf16(ah3, bh, acc3, 0,0,0);
        acc0 = __builtin_amdgcn_mfma_f32_16x16x32_bf16(al0, bh, acc0, 0,0,0);
        acc1 = __builtin_amdgcn_mfma_f32_16x16x32_bf16(al1, bh, acc1, 0,0,0);
        acc2 = __builtin_amdgcn_mfma_f32_16x16x32_bf16(al2, bh, acc2, 0,0,0);
        acc3 = __builtin_amdgcn_mfma_f32_16x16x32_bf16(al3, bh, acc3, 0,0,0);
        acc0 = __builtin_amdgcn_mfma_f32_16x16x32_bf16(ah0, bl, acc0, 0,0,0);
        acc1 = __builtin_amdgcn_mfma_f32_16x16x32_bf16(ah1, bl, acc1, 0,0,0);
        acc2 = __builtin_amdgcn_mfma_f32_16x16x32_bf16(ah2, bl, acc2, 0,0,0);
        acc3 = __builtin_amdgcn_mfma_f32_16x16x32_bf16(ah3, bl, acc3, 0,0,0);
      }
    }
  }
  float bias = Bb[chl];
  int rowb = q*4;
  float* hO = h + (size_t)(offL + nb)*64;
  #pragma unroll
  for (int reg=0;reg<4;++reg){
    int n0 = rowb + reg;
    float v0 = acc0[reg] + bias; if (nb + n0      < N) hO[(size_t)(n0     )*64 + chl] = v0 > 0.f ? v0 : 0.f;
    float v1 = acc1[reg] + bias; if (nb + n0 + 16 < N) hO[(size_t)(n0 + 16)*64 + chl] = v1 > 0.f ? v1 : 0.f;
    float v2 = acc2[reg] + bias; if (nb + n0 + 32 < N) hO[(size_t)(n0 + 32)*64 + chl] = v2 > 0.f ? v2 : 0.f;
    float v3 = acc3[reg] + bias; if (nb + n0 + 48 < N) hO[(size_t)(n0 + 48)*64 + chl] = v3 > 0.f ? v3 : 0.f;
  }
}

// ---------- tail level (on-chip): m-loop reads Pt; pool next Pt from REGISTERS ----------
template<int L>
__device__ __forceinline__ void tail_level2(float* __restrict__ h,
    const unsigned short* __restrict__ WHc, const unsigned short* __restrict__ WLc,
    const float* __restrict__ convB, const float* __restrict__ Hpar,
    unsigned short* __restrict__ PtH, unsigned short* __restrict__ PtL, int t){
  constexpr int Np  = 1 << (2*L);
  constexpr int NTt = (Np + 15)/16;
  constexpr int TG  = (NTt + 3)/4;
  constexpr int res = 1 << L;
  int w  = t >> 6;
  int cb = __builtin_amdgcn_readfirstlane(w & 3);
  int tg = __builtin_amdgcn_readfirstlane(w >> 2);
  int lane = t & 63;
  int q = lane >> 4, li = lane & 15;
  int chl = cb*16 + li;
  int lx[TG], ly[TG];
  #pragma unroll
  for (int i=0;i<TG;++i){
    unsigned n = (unsigned)((tg*TG + i)*16 + li);
    lx[i] = (int)deint(n); ly[i] = (int)deint(n >> 1);
  }
  f32x4 acc[TG];
  #pragma unroll
  for (int i=0;i<TG;++i) acc[i] = f32x4{0.f,0.f,0.f,0.f};
  // B-frag m=0 (named regs), T14 rolling prefetch inside the loop
  short8 bh0, bl0, bh1, bl1;
  {
    size_t f0 = ((size_t)(0*4 + cb)*64 + lane)*8;
    size_t f1 = ((size_t)(1*4 + cb)*64 + lane)*8;
    bh0 = *(const short8*)(WHc + f0); bl0 = *(const short8*)(WLc + f0);
    bh1 = *(const short8*)(WHc + f1); bl1 = *(const short8*)(WLc + f1);
  }
  #pragma unroll 1
  for (int m=0;m<9;++m){
    short8 nh0, nl0, nh1, nl1;
    if (m < 8){
      size_t f0 = ((size_t)(((m+1)*2+0)*4 + cb)*64 + lane)*8;
      size_t f1 = ((size_t)(((m+1)*2+1)*4 + cb)*64 + lane)*8;
      nh0 = *(const short8*)(WHc + f0); nl0 = *(const short8*)(WLc + f0);
      nh1 = *(const short8*)(WHc + f1); nl1 = *(const short8*)(WLc + f1);
    }
    int dy = m/3 - 1, dx = m%3 - 1;
    #pragma unroll
    for (int i=0;i<TG;++i){
      int nx = lx[i]+dx, ny = ly[i]+dy;
      int key = (nx>=0 && ny>=0 && nx<res && ny<res)
              ? (int)(ileave((unsigned)nx) | (ileave((unsigned)ny)<<1)) : Np;
      const unsigned short* pH = PtH + key*72;
      const unsigned short* pL = PtL + key*72;
      short8 ah0 = *(const short8*)(pH + q*8);
      short8 al0 = *(const short8*)(pL + q*8);
      short8 ah1 = *(const short8*)(pH + 32 + q*8);
      short8 al1 = *(const short8*)(pL + 32 + q*8);
      acc[i] = __builtin_amdgcn_mfma_f32_16x16x32_bf16(ah0, bh0, acc[i], 0,0,0);
      acc[i] = __builtin_amdgcn_mfma_f32_16x16x32_bf16(al0, bh0, acc[i], 0,0,0);
      acc[i] = __builtin_amdgcn_mfma_f32_16x16x32_bf16(ah0, bl0, acc[i], 0,0,0);
      acc[i] = __builtin_amdgcn_mfma_f32_16x16x32_bf16(ah1, bh1, acc[i], 0,0,0);
      acc[i] = __builtin_amdgcn_mfma_f32_16x16x32_bf16(al1, bh1, acc[i], 0,0,0);
      acc[i] = __builtin_amdgcn_mfma_f32_16x16x32_bf16(ah1, bl1, acc[i], 0,0,0);
    }
    if (m < 8){ bh0 = nh0; bl0 = nl0; bh1 = nh1; bl1 = nl1; }
  }
  float bias = convB[L*64 + chl];
  float vq[TG][4];
  #pragma unroll
  for (int i=0;i<TG;++i){
    #pragma unroll
    for (int reg=0;reg<4;++reg){
      int ni = (tg*TG + i)*16 + q*4 + reg;
      float v = acc[i][reg] + bias;
      v = v > 0.f ? v : 0.f;
      vq[i][reg] = v;
      if (ni < Np) h[(size_t)(OFFS[L] + ni)*64 + chl] = v;
    }
  }
  __syncthreads();   // all waves done READING Pt(L) before overwriting with Pt(L-1)
  if (L > 1){
    constexpr int Pp = Np/4;   // parents at level L-1
    #pragma unroll
    for (int i=0;i<TG;++i){
      int p = (tg*TG + i)*4 + q;    // lane's reg-quad {4p..4p+3} = children of p
      if (p < Pp){
        float pooled = 0.25f*(vq[i][0]+vq[i][1]+vq[i][2]+vq[i][3])
                     + Hpar[(size_t)(OFFS[L-1] + p)*64 + chl];
        unsigned short hh = f2bh(pooled);
        PtH[p*72 + chl] = hh;
        PtL[p*72 + chl] = f2bh(pooled - bh2f(hh));
      }
    }
    if (t < 64){ PtH[Pp*72 + t] = 0; PtL[Pp*72 + t] = 0; }  // zero row for clamp
  } else {
    // L==1: final h[0] = Hpar[0] + mean(conv-1 outputs 0..3)
    if (tg == 0 && q == 0){
      float pooled = 0.25f*(vq[0][0]+vq[0][1]+vq[0][2]+vq[0][3]) + Hpar[chl];
      h[chl] = pooled;
    }
  }
  __syncthreads();   // Pt(L-1) visible
}

__global__ __launch_bounds__(1024) void k_tail(float* __restrict__ h,
    const unsigned short* __restrict__ WH, const unsigned short* __restrict__ WLo,
    const float* __restrict__ convB){
  __shared__ unsigned short PtH[257*72];
  __shared__ unsigned short PtL[257*72];
  __shared__ float Hpar[85*64];          // h[0..85): levels 0..3 inproj rows
  int t = threadIdx.x;
  for (int e = t; e < 85*16; e += 1024)
    ((float4*)Hpar)[e] = ((const float4*)h)[e];
  // stage Pt for L=4: pooled = 0.25*sum(children h[5]) + parent h[4]; row 256 = zero
  for (int e = t; e < 257*16; e += 1024){
    int node = e >> 4, u = e & 15;
    float4 r = make_float4(0.f,0.f,0.f,0.f);
    if (node < 256){
      const float4* c = (const float4*)(h + (size_t)(OFFS[5] + 4*node)*64) + u;
      float4 c0 = c[0], c1 = c[16], c2 = c[32], c3 = c[48];
      float4 pr = *((const float4*)(h + (size_t)(OFFS[4] + node)*64) + u);
      r.x = 0.25f*(c0.x+c1.x+c2.x+c3.x) + pr.x;
      r.y = 0.25f*(c0.y+c1.y+c2.y+c3.y) + pr.y;
      r.z = 0.25f*(c0.z+c1.z+c2.z+c3.z) + pr.z;
      r.w = 0.25f*(c0.w+c1.w+c2.w+c3.w) + pr.w;
    }
    unsigned short h0=f2bh(r.x), h1=f2bh(r.y), h2=f2bh(r.z), h3=f2bh(r.w);
    *(ushort4*)&PtH[node*72 + u*4] = make_ushort4(h0,h1,h2,h3);
    *(ushort4*)&PtL[node*72 + u*4] = make_ushort4(
        f2bh(r.x - bh2f(h0)), f2bh(r.y - bh2f(h1)),
        f2bh(r.z - bh2f(h2)), f2bh(r.w - bh2f(h3)));
  }
  __syncthreads();
  tail_level2<4>(h, WH + (size_t)3*36864, WLo + (size_t)3*36864, convB, Hpar, PtH, PtL, t);
  tail_level2<3>(h, WH + (size_t)2*36864, WLo + (size_t)2*36864, convB, Hpar, PtH, PtL, t);
  tail_level2<2>(h, WH + (size_t)1*36864, WLo + (size_t)1*36864, convB, Hpar, PtH, PtL, t);
  tail_level2<1>(h, WH,                   WLo,                   convB, Hpar, PtH, PtL, t);
}

// ---------- emb + LN (MFMA; wave = M-tile, cb looped in-register; zero LDS) ----------
__global__ __launch_bounds__(256) void k_emb(float* __restrict__ h,
    const unsigned short* __restrict__ EH, const unsigned short* __restrict__ ELo,
    const float* __restrict__ embB, const float* __restrict__ lng,
    const float* __restrict__ lnb, const float* __restrict__ gain){
  int bb = blockIdx.x;
  int d = 0;
  #pragma unroll
  for (int i=1;i<=9;++i) if (bb >= EB64[i]) d = i;
  int nb = (bb - EB64[d]) * 64;
  int N = 1 << (2*d);
  int off = OFFS[d];
  int t = threadIdx.x;
  int wt = __builtin_amdgcn_readfirstlane(t >> 6);   // wave = M-tile (16 nodes)
  int lane = t & 63;
  int q = lane >> 4, li = lane & 15;

  // A fragments: this wave's 16 rows, loaded+split ONCE
  const float* rp = h + ((size_t)off + nb + wt*16 + li)*64 + q*8;
  float4 a0 = *(const float4*)rp;
  float4 a1 = *(const float4*)(rp + 4);
  float4 a2 = *(const float4*)(rp + 32);
  float4 a3 = *(const float4*)(rp + 36);
  short8 ah0, al0, ah1, al1;
  split8(a0, a1, ah0, al0);
  split8(a2, a3, ah1, al1);

  f32x4 acc0 = {0.f,0.f,0.f,0.f}, acc1 = acc0, acc2 = acc0, acc3 = acc0;
  #define EMB_CB(CB, ACC) { \
    size_t f0 = (((size_t)(d*2+0)*4 + (CB))*64 + lane)*8; \
    size_t f1 = (((size_t)(d*2+1)*4 + (CB))*64 + lane)*8; \
    short8 bh0 = *(const short8*)(EH + f0); \
    short8 bl0 = *(const short8*)(ELo + f0); \
    short8 bh1 = *(const short8*)(EH + f1); \
    short8 bl1 = *(const short8*)(ELo + f1); \
    ACC = __builtin_amdgcn_mfma_f32_16x16x32_bf16(ah0, bh0, ACC, 0,0,0); \
    ACC = __builtin_amdgcn_mfma_f32_16x16x32_bf16(al0, bh0, ACC, 0,0,0); \
    ACC = __builtin_amdgcn_mfma_f32_16x16x32_bf16(ah0, bl0, ACC, 0,0,0); \
    ACC = __builtin_amdgcn_mfma_f32_16x16x32_bf16(ah1, bh1, ACC, 0,0,0); \
    ACC = __builtin_amdgcn_mfma_f32_16x16x32_bf16(al1, bh1, ACC, 0,0,0); \
    ACC = __builtin_amdgcn_mfma_f32_16x16x32_bf16(ah1, bl1, ACC, 0,0,0); }
  EMB_CB(0, acc0)
  EMB_CB(1, acc1)
  EMB_CB(2, acc2)
  EMB_CB(3, acc3)
  #undef EMB_CB

  float b0 = embB[d*64 +      li];
  float b1 = embB[d*64 + 16 + li];
  float b2 = embB[d*64 + 32 + li];
  float b3 = embB[d*64 + 48 + li];
  float mu[4], rs[4];
  float z0[4], z1[4], z2[4], z3[4];
  #pragma unroll
  for (int r=0;r<4;++r){
    z0[r] = acc0[r] + b0;
    z1[r] = acc1[r] + b1;
    z2[r] = acc2[r] + b2;
    z3[r] = acc3[r] + b3;
    float s  = z0[r] + z1[r] + z2[r] + z3[r];
    float qv = z0[r]*z0[r] + z1[r]*z1[r] + z2[r]*z2[r] + z3[r]*z3[r];
    #pragma unroll
    for (int mk=1; mk<16; mk<<=1){
      s  += __shfl_xor(s, mk, 64);
      qv += __shfl_xor(qv, mk, 64);
    }
    float m = s * 0.015625f;
    mu[r] = m;
    rs[r] = rsqrtf(qv * 0.015625f - m*m + 1e-5f);
  }
  float g0 = lng[d*64 +      li], l0 = lnb[d*64 +      li];
  float g1 = lng[d*64 + 16 + li], l1 = lnb[d*64 + 16 + li];
  float g2 = lng[d*64 + 32 + li], l2 = lnb[d*64 + 32 + li];
  float g3 = lng[d*64 + 48 + li], l3 = lnb[d*64 + 48 + li];
  float gn = gain[d];
  #pragma unroll
  for (int r=0;r<4;++r){
    int ni = wt*16 + q*4 + r;
    if (nb + ni < N){
      float* row = h + ((size_t)off + nb + ni)*64;
      row[     li] = ((z0[r] - mu[r])*rs[r]*g0 + l0)*gn;
      row[16 + li] = ((z1[r] - mu[r])*rs[r]*g1 + l1)*gn;
      row[32 + li] = ((z2[r] - mu[r])*rs[r]*g2 + l2)*gn;
      row[48 + li] = ((z3[r] - mu[r])*rs[r]*g3 + l3)*gn;
    }
  }
}

extern "C" void kernel_launch(void* const* d_in, const int* in_sizes, int n_in,
                              void* d_out, int out_size, void* d_ws, size_t ws_size,
                              hipStream_t stream) {
  (void)in_sizes; (void)n_in; (void)out_size;
  const float* feat  = (const float*)d_in[0];
  const float* ipW   = (const float*)d_in[1];
  const float* ipB   = (const float*)d_in[2];
  const float* convW = (const float*)d_in[3];
  const float* convB = (const float*)d_in[4];
  const float* embW  = (const float*)d_in[5];
  const float* embB  = (const float*)d_in[6];
  const float* lng   = (const float*)d_in[7];
  const float* lnb   = (const float*)d_in[8];
  const float* gain  = (const float*)d_in[9];
  float* h = (float*)d_out;

  unsigned short* WH  = (unsigned short*)d_ws;
  unsigned short* WLo = WH + FRAG_USH;
  float* hpre = (ws_size >= FRAG_BYTES + HPRE_BYTES)
              ? (float*)((char*)d_ws + FRAG_BYTES) : nullptr;

  k_wprep<<<164, 256, 0, stream>>>(convW, embW, WH, WLo);
  k_inproj<<<(TOTAL + 127)/128, 256, 0, stream>>>(feat, ipW, ipB, h, hpre);

  // levels L=8..5 on the grid; L=4..1 inside k_tail (on-chip pooling)
  for (int L = 8; L >= 5; --L){
    int Np = 1 << (2*L);
    const float* hPar = hpre ? (hpre + (size_t)(OFFS[L] - OFFS[4])*64)
                             : (h + (size_t)OFFS[L]*64);
    k_conv<<<Np/64, 256, 0, stream>>>(h, hPar,
        WH  + (size_t)(L-1)*36864, WLo + (size_t)(L-1)*36864,
        convB + (size_t)L*64, Np, OFFS[L], OFFS[L+1], L);
  }

  k_tail<<<1, 1024, 0, stream>>>(h, WH, WLo, convB);
  k_emb<<<5464, 256, 0, stream>>>(h, WH + CONV_USH, WLo + CONV_USH,
                                  embB, lng, lnb, gain);
}